// Round 10
// baseline (288.457 us; speedup 1.0000x reference)
//
#include <hip/hip_runtime.h>
#include <stdint.h>

#define BTOK 32768
#define DIN 256
#define DHID 512
#define DOUT 256
#define NEXP 16
#define BM 128
#define CH 32
#define NCH 16
#define SLOTS 96

typedef __attribute__((ext_vector_type(8))) short bf16x8;
typedef __attribute__((ext_vector_type(4))) float f32x4;

__device__ __forceinline__ unsigned short f2bf(float f){
  unsigned u = __builtin_bit_cast(unsigned, f);
  u = u + 0x7FFFu + ((u >> 16) & 1u);      // RNE, finite inputs only
  return (unsigned short)(u >> 16);
}
__device__ __forceinline__ float bf2f(unsigned short h){
  return __builtin_bit_cast(float, (unsigned)h << 16);
}
__device__ __forceinline__ void gload16(const void* g, void* l){
  __builtin_amdgcn_global_load_lds((const __attribute__((address_space(1))) unsigned int*)g,
                                   (__attribute__((address_space(3))) unsigned int*)l, 16, 0, 0);
}

// ---------------- W1 transpose + cvt: src[e][256 i][512 h] -> dst[e][512 h][256 i]
__global__ __launch_bounds__(256) void transpose_cvt(const float* __restrict__ src,
                                                     unsigned short* __restrict__ dst,
                                                     int R, int C){
  __shared__ float t[32][33];
  int e = blockIdx.z, r0 = blockIdx.y * 32, c0 = blockIdx.x * 32;
  int lx = threadIdx.x & 31, ly = threadIdx.x >> 5;
  const float* s = src + (size_t)e * R * C;
  unsigned short* d = dst + (size_t)e * R * C;
#pragma unroll
  for (int i = 0; i < 4; i++){ int r = ly + i * 8; t[r][lx] = s[(size_t)(r0 + r) * C + c0 + lx]; }
  __syncthreads();
#pragma unroll
  for (int i = 0; i < 4; i++){ int r = ly + i * 8; d[(size_t)(c0 + r) * R + r0 + lx] = f2bf(t[lx][r]); }
}

// ---------------- W2 transpose + cvt into chunk-major: src[e][512 h][256 o] -> dst[e][16][256 o][32 h]
__global__ __launch_bounds__(256) void transpose_cvt_w2(const float* __restrict__ src,
                                                        unsigned short* __restrict__ dst){
  __shared__ float t[32][33];
  int e = blockIdx.z, r0 = blockIdx.y * 32, c0 = blockIdx.x * 32;   // r0 over h, c0 over o
  int lx = threadIdx.x & 31, ly = threadIdx.x >> 5;
  const float* s = src + (size_t)e * DHID * DOUT;
  unsigned short* d = dst + (size_t)e * DHID * DOUT + (r0 >> 5) * (DOUT * CH);
#pragma unroll
  for (int i = 0; i < 4; i++){ int r = ly + i * 8; t[r][lx] = s[(size_t)(r0 + r) * DOUT + c0 + lx]; }
  __syncthreads();
#pragma unroll
  for (int i = 0; i < 4; i++){ int rr = ly + i * 8; d[(size_t)(c0 + rr) * CH + lx] = f2bf(t[lx][rr]); }
}

// ---------------- gating: 512 blocks x 64 tokens; LDS-aggregated histogram
__global__ __launch_bounds__(256) void gating_kernel(const float* __restrict__ x,
                                                     const float* __restrict__ Wg,
                                                     const float* __restrict__ bg,
                                                     unsigned short* __restrict__ x_bf,
                                                     int* __restrict__ top_idx,
                                                     float* __restrict__ top_w,
                                                     int* __restrict__ counts){
  __shared__ float WgT[16][256];
  __shared__ int hist[16];
  int tid = threadIdx.x;
#pragma unroll
  for (int j = 0; j < 4; j++){
    float4 wv = *(const float4*)(Wg + tid * 16 + j * 4);
    WgT[j * 4 + 0][tid] = wv.x; WgT[j * 4 + 1][tid] = wv.y;
    WgT[j * 4 + 2][tid] = wv.z; WgT[j * 4 + 3][tid] = wv.w;
  }
  if (tid < 16) hist[tid] = 0;
  __syncthreads();
  int wid = tid >> 6, lane = tid & 63;

  for (int t = 0; t < 16; t++){
    int tok = blockIdx.x * 64 + wid * 16 + t;
    const float4 xv = *(const float4*)(x + (size_t)tok * DIN + lane * 4);
    ushort4 xb; xb.x = f2bf(xv.x); xb.y = f2bf(xv.y); xb.z = f2bf(xv.z); xb.w = f2bf(xv.w);
    *(ushort4*)(x_bf + (size_t)tok * DIN + lane * 4) = xb;
    float logit[16];
#pragma unroll
    for (int e = 0; e < 16; e++){
      const float4 wv = *(const float4*)(&WgT[e][lane * 4]);
      float v = xv.x * wv.x + xv.y * wv.y + xv.z * wv.z + xv.w * wv.w;
#pragma unroll
      for (int off = 32; off; off >>= 1) v += __shfl_xor(v, off, 64);
      logit[e] = v + bg[e];
    }
    if (lane == 0){
      int i1 = 0; float v1 = logit[0];
#pragma unroll
      for (int e = 1; e < 16; e++) if (logit[e] > v1){ v1 = logit[e]; i1 = e; }
      int i2 = -1; float v2 = -3.4e38f;
#pragma unroll
      for (int e = 0; e < 16; e++) if (e != i1 && logit[e] > v2){ v2 = logit[e]; i2 = e; }
      float tt = expf(v2 - v1);
      float w1 = 1.0f / (1.0f + tt);
      float w2 = tt / (1.0f + tt);
      top_idx[tok * 2] = i1; top_idx[tok * 2 + 1] = i2;
      top_w[tok * 2] = w1;  top_w[tok * 2 + 1] = w2;
      atomicAdd(&hist[i1], 1); atomicAdd(&hist[i2], 1);
    }
  }
  __syncthreads();
  if (tid < 16) atomicAdd(&counts[tid], hist[tid]);
}

// ---------------- prefix sum + XCD-affine block map (one wave)
__global__ void prefix_kernel(const int* __restrict__ counts, int* __restrict__ offsets,
                              int* __restrict__ cursor, int* __restrict__ bm_e,
                              int* __restrict__ bm_start, int* __restrict__ bm_end){
  int lane = threadIdx.x & 63;
  int c = (lane < 16) ? counts[lane] : 0;
  int s = c;
#pragma unroll
  for (int off = 1; off < 16; off <<= 1){ int o = __shfl_up(s, off, 64); if (lane >= off) s += o; }
  int start = s - c;
  if (lane < 16){ offsets[lane] = start; cursor[lane] = start; }
  int nb = (c + BM - 1) >> 7;
  int nb_partner = __shfl(nb, lane ^ 8, 64);
  if (lane < 8){
    int filled = nb + nb_partner;
    if (filled > SLOTS) filled = SLOTS;
    for (int i = filled; i < SLOTS; i++) bm_e[lane * SLOTS + i] = -1;
  }
  if (lane < 16){
    int sbase = (lane < 8) ? 0 : nb_partner;
    int xcd = lane & 7;
    for (int b = 0; b < nb; b++){
      int idx = xcd * SLOTS + sbase + b;
      if (sbase + b < SLOTS){
        bm_e[idx] = lane; bm_start[idx] = start + b * BM; bm_end[idx] = start + c;
      }
    }
  }
}

// ---------------- scatter: block-aggregated chunk reservation, LDS ranks
__global__ __launch_bounds__(256) void scatter_kernel(const int* __restrict__ top_idx,
                                                      const float* __restrict__ top_w,
                                                      int* __restrict__ cursor,
                                                      int* __restrict__ pair_tok,
                                                      float* __restrict__ pair_w,
                                                      int* __restrict__ pair_slot){
  __shared__ int hist[16], base[16], rank[16];
  int tid = threadIdx.x;
  if (tid < 16){ hist[tid] = 0; rank[tid] = 0; }
  __syncthreads();
  int t = blockIdx.x * 256 + tid;
  int e0 = top_idx[t * 2], e1 = top_idx[t * 2 + 1];
  float w0 = top_w[t * 2], w1 = top_w[t * 2 + 1];
  atomicAdd(&hist[e0], 1); atomicAdd(&hist[e1], 1);
  __syncthreads();
  if (tid < 16) base[tid] = atomicAdd(&cursor[tid], hist[tid]);
  __syncthreads();
  int r0 = atomicAdd(&rank[e0], 1);
  int p0 = base[e0] + r0;
  pair_tok[p0] = t; pair_w[p0] = w0; pair_slot[t * 2] = p0;
  int r1 = atomicAdd(&rank[e1], 1);
  int p1 = base[e1] + r1;
  pair_tok[p1] = t; pair_w[p1] = w1; pair_slot[t * 2 + 1] = p1;
}

// ---------------- fused 2-layer expert MLP v10: 128 pairs/block, 8 waves, M=16/wave
// Register diet to <=128 total (xr 32 + acc 64 AGPR + temps) via
// __launch_bounds__(512,4) -> 4 waves/SIMD -> TWO 8-wave blocks per CU,
// all 512 blocks resident simultaneously (zero serial turnover).
// W1+W2 both dbuf-LDS (shared by 8 waves); per-wave hs -> 1 barrier/chunk.
__global__ __launch_bounds__(512, 4) void moe_gemm_kernel(
    const unsigned short* __restrict__ x_bf,   // [B][256]
    const unsigned short* __restrict__ W1t,    // [E][512 h][256 i]
    const unsigned short* __restrict__ W2c,    // [E][16 c][256 o][32 h]
    const float* __restrict__ b1,              // [E][512]
    const float* __restrict__ b2,              // [E][256]
    const int* __restrict__ pair_tok, const float* __restrict__ pair_w,
    const int* __restrict__ bm_e, const int* __restrict__ bm_start,
    const int* __restrict__ bm_end,
    unsigned short* __restrict__ ypair){       // [65536][256] bf16
  int xcd = blockIdx.x & 7, slot = blockIdx.x >> 3;
  int bmi = xcd * SLOTS + slot;
  int e = bm_e[bmi];
  if (e < 0) return;
  int rs = bm_start[bmi], re = bm_end[bmi];

  __shared__ unsigned short w1s[2][CH * 256];   // 2x16KB [h row][i], 512B rows, XOR(bits4-6)
  __shared__ unsigned short w2s[2][256 * CH];   // 2x16KB [o row][h], row-pair 128B XOR
  __shared__ unsigned short hsm[8][16 * CH];    // 8KB, per-wave [m 16][h 32], row-pair XOR
  __shared__ float b1s[DHID];                   // 2KB

  int tid = threadIdx.x, wid = tid >> 6, lane = tid & 63, lr = lane & 15, lh = lane >> 4;
  char* hsb = (char*)hsm[wid];
  const char* gW1 = (const char*)(W1t + (size_t)e * DHID * DIN);
  const char* gW2 = (const char*)(W2c + (size_t)e * DOUT * DHID);

  b1s[tid] = b1[e * DHID + tid];

  // per-lane staging source offsets (pre-swizzled, proven R6/R9 mappings)
  int o1 = ((tid >> 5) * 512) + (((tid & 31) ^ ((tid >> 5) & 7)) * 16);
  int o2;
  { int p = tid >> 3, q = (tid & 7) ^ (p & 7);
    o2 = (p * 2 + (q >> 2)) * 64 + (q & 3) * 16; }

  // ---- x rows (wave's 16 tokens) -> registers (32 VGPR)
  int g0 = rs + 16 * wid + lr;
  int gc = g0 < re ? g0 : (re - 1);
  int tok = pair_tok[gc];
  bf16x8 xr[8];
  {
    const unsigned short* xrow = x_bf + (size_t)tok * DIN + lh * 8;
#pragma unroll
    for (int ks = 0; ks < 8; ks++) xr[ks] = *(const bf16x8*)(xrow + ks * 32);
  }

#define STAGE(c, sl) {                                                    \
    const char* s1 = gW1 + (size_t)(c) * 16384;                           \
    const char* s2 = gW2 + (size_t)(c) * 16384;                           \
    char* d1 = (char*)w1s[sl]; char* d2 = (char*)w2s[sl];                 \
    gload16(s1 + o1,        d1 + tid * 16);                               \
    gload16(s1 + o1 + 8192, d1 + tid * 16 + 8192);                        \
    gload16(s2 + o2,        d2 + tid * 16);                               \
    gload16(s2 + o2 + 8192, d2 + tid * 16 + 8192);                        \
  }

  f32x4 acc[16];
#pragma unroll
  for (int i = 0; i < 16; i++) acc[i] = (f32x4){0.f, 0.f, 0.f, 0.f};

  STAGE(0, 0);
  __syncthreads();                       // chunk-0 staged; b1s ready

  for (int c = 0; c < NCH; c++){
    int sl = c & 1;
    if (c + 1 < NCH) STAGE(c + 1, sl ^ 1);   // in flight under this chunk's compute

    // ---- phase A: h[16 tok][32 hid] = x @ W1c  (A regs, B from w1s[sl])
    const char* w1b = (const char*)w1s[sl];
    f32x4 hacc0 = (f32x4){0.f, 0.f, 0.f, 0.f};
    f32x4 hacc1 = (f32x4){0.f, 0.f, 0.f, 0.f};
#pragma unroll
    for (int ks = 0; ks < 8; ks++){
      int r0 = lr, r1 = 16 + lr;
      bf16x8 b0 = *(const bf16x8*)(w1b + ((r0 * 512 + ks * 64 + lh * 16) ^ ((r0 & 7) << 4)));
      bf16x8 b1f = *(const bf16x8*)(w1b + ((r1 * 512 + ks * 64 + lh * 16) ^ ((r1 & 7) << 4)));
      hacc0 = __builtin_amdgcn_mfma_f32_16x16x32_bf16(xr[ks], b0, hacc0, 0, 0, 0);
      hacc1 = __builtin_amdgcn_mfma_f32_16x16x32_bf16(xr[ks], b1f, hacc1, 0, 0, 0);
    }

    // ---- relu(h+b1) -> wave-private hs (row-pair XOR layout; no barrier)
    {
      float bv0 = b1s[c * CH + lr];
      float bv1 = b1s[c * CH + 16 + lr];
#pragma unroll
      for (int r = 0; r < 4; r++){
        int m = lh * 4 + r;
        int basem = (m >> 1) * 128;
        int swz = ((m >> 1) & 7) << 4;
        int hi6 = (m & 1) << 6;
        float v0 = fmaxf(hacc0[r] + bv0, 0.f);
        float v1 = fmaxf(hacc1[r] + bv1, 0.f);
        *(unsigned short*)(hsb + basem + ((hi6 + lr * 2) ^ swz)) = f2bf(v0);
        *(unsigned short*)(hsb + basem + ((hi6 + 32 + lr * 2) ^ swz)) = f2bf(v1);
      }
    }

    // ---- phase B: y[16 tok][256 out] += h @ W2c  (A from own hs, B from w2s[sl])
    bf16x8 ha;
    {
      int hadr = (lr >> 1) * 128 + ((((lr & 1) << 6) + (lh << 4)) ^ (((lr >> 1) & 7) << 4));
      ha = *(const bf16x8*)(hsb + hadr);
    }
    const char* w2b = (const char*)w2s[sl];
#pragma unroll
    for (int nt = 0; nt < 16; nt++){
      int n = nt * 16 + lr;
      int adr = (n >> 1) * 128 + ((((n & 1) << 6) + (lh << 4)) ^ (((n >> 1) & 7) << 4));
      bf16x8 b = *(const bf16x8*)(w2b + adr);
      acc[nt] = __builtin_amdgcn_mfma_f32_16x16x32_bf16(ha, b, acc[nt], 0, 0, 0);
    }
    __syncthreads();   // next chunk staged; all reads of slot sl complete
  }

  // ---- epilogue: fold gate weight + b2, store per-pair bf16 rows
  {
    float wrow[4]; int grow[4];
#pragma unroll
    for (int r = 0; r < 4; r++){
      int gg = rs + 16 * wid + lh * 4 + r;
      grow[r] = gg;
      wrow[r] = (gg < re) ? pair_w[gg] : 0.f;
    }
#pragma unroll
    for (int nt = 0; nt < 16; nt++){
      int col = nt * 16 + lr;
      float b2v = b2[e * DOUT + col];
#pragma unroll
      for (int r = 0; r < 4; r++){
        if (grow[r] < re)
          ypair[(size_t)grow[r] * DOUT + col] = f2bf(wrow[r] * (acc[nt][r] + b2v));
      }
    }
  }
#undef STAGE
}

// ---------------- combine two pair rows per token
__global__ __launch_bounds__(256) void combine_kernel(const unsigned short* __restrict__ yp,
                                                      const int* __restrict__ pair_slot,
                                                      float* __restrict__ out){
  int idx = blockIdx.x * 256 + threadIdx.x;
  int t = idx >> 6;
  int c4 = (idx & 63) << 2;
  int s0 = pair_slot[t * 2], s1 = pair_slot[t * 2 + 1];
  ushort4 a = *(const ushort4*)(yp + (size_t)s0 * DOUT + c4);
  ushort4 b = *(const ushort4*)(yp + (size_t)s1 * DOUT + c4);
  float4 o;
  o.x = bf2f(a.x) + bf2f(b.x);
  o.y = bf2f(a.y) + bf2f(b.y);
  o.z = bf2f(a.z) + bf2f(b.z);
  o.w = bf2f(a.w) + bf2f(b.w);
  *(float4*)(out + (size_t)t * DOUT + c4) = o;
}

extern "C" void kernel_launch(void* const* d_in, const int* in_sizes, int n_in,
                              void* d_out, int out_size, void* d_ws, size_t ws_size,
                              hipStream_t stream){
  (void)in_sizes; (void)n_in; (void)out_size; (void)ws_size;
  const float* x  = (const float*)d_in[0];
  const float* Wg = (const float*)d_in[1];
  const float* bg = (const float*)d_in[2];
  const float* W1 = (const float*)d_in[3];
  const float* b1 = (const float*)d_in[4];
  const float* W2 = (const float*)d_in[5];
  const float* b2 = (const float*)d_in[6];
  float* out = (float*)d_out;
  char* ws = (char*)d_ws;

  unsigned short* x_bf  = (unsigned short*)(ws);                 // 16,777,216
  unsigned short* W1t   = (unsigned short*)(ws + 16777216);      //  4,194,304
  unsigned short* W2ck  = (unsigned short*)(ws + 20971520);      //  4,194,304
  unsigned short* ypair = (unsigned short*)(ws + 25165824);      // 33,554,432
  int*   top_idx  = (int*)  (ws + 58720256);
  float* top_w    = (float*)(ws + 58982400);
  int*   pair_tok = (int*)  (ws + 59244544);
  float* pair_w   = (float*)(ws + 59506688);
  int*   pair_slot= (int*)  (ws + 59768832);
  int*   counts   = (int*)  (ws + 60030976);
  int*   offsets  = (int*)  (ws + 60031040);
  int*   cursor   = (int*)  (ws + 60031104);
  int*   bm_e     = (int*)  (ws + 60031232);   // 768 ints
  int*   bm_start = (int*)  (ws + 60036608);   // 768 ints
  int*   bm_end   = (int*)  (ws + 60041984);   // 768 ints

  hipMemsetAsync(counts, 0, 64, stream);
  transpose_cvt<<<dim3(16, 8, 16), 256, 0, stream>>>(W1, W1t, 256, 512);
  transpose_cvt_w2<<<dim3(8, 16, 16), 256, 0, stream>>>(W2, W2ck);
  gating_kernel<<<512, 256, 0, stream>>>(x, Wg, bg, x_bf, top_idx, top_w, counts);
  prefix_kernel<<<1, 64, 0, stream>>>(counts, offsets, cursor, bm_e, bm_start, bm_end);
  scatter_kernel<<<128, 256, 0, stream>>>(top_idx, top_w, cursor, pair_tok, pair_w, pair_slot);
  moe_gemm_kernel<<<8 * SLOTS, 512, 0, stream>>>(x_bf, W1t, W2ck, b1, b2, pair_tok, pair_w,
                                                 bm_e, bm_start, bm_end, ypair);
  combine_kernel<<<8192, 256, 0, stream>>>(ypair, pair_slot, out);
}

// Round 11
// 215.430 us; speedup vs baseline: 1.3390x; 1.3390x over previous
//
#include <hip/hip_runtime.h>
#include <stdint.h>

#define BTOK 32768
#define DIN 256
#define DHID 512
#define DOUT 256
#define NEXP 16
#define BM 128
#define CH 32
#define NCH 16
#define SLOTS 96

typedef __attribute__((ext_vector_type(8))) short bf16x8;
typedef __attribute__((ext_vector_type(4))) float f32x4;

__device__ __forceinline__ unsigned short f2bf(float f){
  unsigned u = __builtin_bit_cast(unsigned, f);
  u = u + 0x7FFFu + ((u >> 16) & 1u);      // RNE, finite inputs only
  return (unsigned short)(u >> 16);
}
__device__ __forceinline__ float bf2f(unsigned short h){
  return __builtin_bit_cast(float, (unsigned)h << 16);
}
__device__ __forceinline__ void gload16(const void* g, void* l){
  __builtin_amdgcn_global_load_lds((const __attribute__((address_space(1))) unsigned int*)g,
                                   (__attribute__((address_space(3))) unsigned int*)l, 16, 0, 0);
}

// ---------------- fused prep: W1 transpose + W2 transpose + gating in ONE launch
// blocks 0..2047: W1 [e][256 i][512 h] -> W1t [e][512 h][256 i]
// blocks 2048..4095: W2 [e][512 h][256 o] -> W2ck [e][16][256 o][32 h]
// blocks 4096..4607: gating (64 tokens/block)
__global__ __launch_bounds__(256) void prep_kernel(const float* __restrict__ x,
                                                   const float* __restrict__ Wg,
                                                   const float* __restrict__ bg,
                                                   const float* __restrict__ W1,
                                                   const float* __restrict__ W2,
                                                   unsigned short* __restrict__ W1t,
                                                   unsigned short* __restrict__ W2ck,
                                                   unsigned short* __restrict__ x_bf,
                                                   int* __restrict__ top_idx,
                                                   float* __restrict__ top_w,
                                                   int* __restrict__ counts){
  __shared__ float tsh[32][33];
  __shared__ float WgT[16][256];
  __shared__ int hist[16];
  int bid = blockIdx.x;
  int tid = threadIdx.x;

  if (bid < 2048){
    // ---- transpose+cvt W1 (R=256 i, C=512 h): dst[e][h][i]
    int bx = bid & 15, by = (bid >> 4) & 7, bz = bid >> 7;
    int r0 = by * 32, c0 = bx * 32;
    int lx = tid & 31, ly = tid >> 5;
    const float* s = W1 + (size_t)bz * 256 * 512;
    unsigned short* d = W1t + (size_t)bz * 256 * 512;
#pragma unroll
    for (int i = 0; i < 4; i++){ int r = ly + i * 8; tsh[r][lx] = s[(size_t)(r0 + r) * 512 + c0 + lx]; }
    __syncthreads();
#pragma unroll
    for (int i = 0; i < 4; i++){ int r = ly + i * 8; d[(size_t)(c0 + r) * 256 + r0 + lx] = f2bf(tsh[lx][r]); }
  } else if (bid < 4096){
    // ---- transpose+cvt W2 into chunk-major [e][16][256 o][32 h]
    int b2 = bid - 2048;
    int bx = b2 & 7, by = (b2 >> 3) & 15, bz = b2 >> 7;
    int r0 = by * 32, c0 = bx * 32;          // r0 over h, c0 over o
    int lx = tid & 31, ly = tid >> 5;
    const float* s = W2 + (size_t)bz * DHID * DOUT;
    unsigned short* d = W2ck + (size_t)bz * DHID * DOUT + (r0 >> 5) * (DOUT * CH);
#pragma unroll
    for (int i = 0; i < 4; i++){ int r = ly + i * 8; tsh[r][lx] = s[(size_t)(r0 + r) * DOUT + c0 + lx]; }
    __syncthreads();
#pragma unroll
    for (int i = 0; i < 4; i++){ int rr = ly + i * 8; d[(size_t)(c0 + rr) * CH + lx] = f2bf(tsh[lx][rr]); }
  } else {
    // ---- gating: 64 tokens per block
    int gb = bid - 4096;
#pragma unroll
    for (int j = 0; j < 4; j++){
      float4 wv = *(const float4*)(Wg + tid * 16 + j * 4);
      WgT[j * 4 + 0][tid] = wv.x; WgT[j * 4 + 1][tid] = wv.y;
      WgT[j * 4 + 2][tid] = wv.z; WgT[j * 4 + 3][tid] = wv.w;
    }
    if (tid < 16) hist[tid] = 0;
    __syncthreads();
    int wid = tid >> 6, lane = tid & 63;
    for (int t = 0; t < 16; t++){
      int tok = gb * 64 + wid * 16 + t;
      const float4 xv = *(const float4*)(x + (size_t)tok * DIN + lane * 4);
      ushort4 xb; xb.x = f2bf(xv.x); xb.y = f2bf(xv.y); xb.z = f2bf(xv.z); xb.w = f2bf(xv.w);
      *(ushort4*)(x_bf + (size_t)tok * DIN + lane * 4) = xb;
      float logit[16];
#pragma unroll
      for (int e = 0; e < 16; e++){
        const float4 wv = *(const float4*)(&WgT[e][lane * 4]);
        float v = xv.x * wv.x + xv.y * wv.y + xv.z * wv.z + xv.w * wv.w;
#pragma unroll
        for (int off = 32; off; off >>= 1) v += __shfl_xor(v, off, 64);
        logit[e] = v + bg[e];
      }
      if (lane == 0){
        int i1 = 0; float v1 = logit[0];
#pragma unroll
        for (int e = 1; e < 16; e++) if (logit[e] > v1){ v1 = logit[e]; i1 = e; }
        int i2 = -1; float v2 = -3.4e38f;
#pragma unroll
        for (int e = 0; e < 16; e++) if (e != i1 && logit[e] > v2){ v2 = logit[e]; i2 = e; }
        float tt = expf(v2 - v1);
        float w1 = 1.0f / (1.0f + tt);
        float w2 = tt / (1.0f + tt);
        top_idx[tok * 2] = i1; top_idx[tok * 2 + 1] = i2;
        top_w[tok * 2] = w1;  top_w[tok * 2 + 1] = w2;
        atomicAdd(&hist[i1], 1); atomicAdd(&hist[i2], 1);
      }
    }
    __syncthreads();
    if (tid < 16) atomicAdd(&counts[tid], hist[tid]);
  }
}

// ---------------- prefix sum + XCD-affine block map (one wave)
__global__ void prefix_kernel(const int* __restrict__ counts, int* __restrict__ offsets,
                              int* __restrict__ cursor, int* __restrict__ bm_e,
                              int* __restrict__ bm_start, int* __restrict__ bm_end){
  int lane = threadIdx.x & 63;
  int c = (lane < 16) ? counts[lane] : 0;
  int s = c;
#pragma unroll
  for (int off = 1; off < 16; off <<= 1){ int o = __shfl_up(s, off, 64); if (lane >= off) s += o; }
  int start = s - c;
  if (lane < 16){ offsets[lane] = start; cursor[lane] = start; }
  int nb = (c + BM - 1) >> 7;
  int nb_partner = __shfl(nb, lane ^ 8, 64);
  if (lane < 8){
    int filled = nb + nb_partner;
    if (filled > SLOTS) filled = SLOTS;
    for (int i = filled; i < SLOTS; i++) bm_e[lane * SLOTS + i] = -1;
  }
  if (lane < 16){
    int sbase = (lane < 8) ? 0 : nb_partner;
    int xcd = lane & 7;
    for (int b = 0; b < nb; b++){
      int idx = xcd * SLOTS + sbase + b;
      if (sbase + b < SLOTS){
        bm_e[idx] = lane; bm_start[idx] = start + b * BM; bm_end[idx] = start + c;
      }
    }
  }
}

// ---------------- scatter: block-aggregated chunk reservation, LDS ranks
__global__ __launch_bounds__(256) void scatter_kernel(const int* __restrict__ top_idx,
                                                      const float* __restrict__ top_w,
                                                      int* __restrict__ cursor,
                                                      int* __restrict__ pair_tok,
                                                      float* __restrict__ pair_w,
                                                      int* __restrict__ pair_slot){
  __shared__ int hist[16], base[16], rank[16];
  int tid = threadIdx.x;
  if (tid < 16){ hist[tid] = 0; rank[tid] = 0; }
  __syncthreads();
  int t = blockIdx.x * 256 + tid;
  int e0 = top_idx[t * 2], e1 = top_idx[t * 2 + 1];
  float w0 = top_w[t * 2], w1 = top_w[t * 2 + 1];
  atomicAdd(&hist[e0], 1); atomicAdd(&hist[e1], 1);
  __syncthreads();
  if (tid < 16) base[tid] = atomicAdd(&cursor[tid], hist[tid]);
  __syncthreads();
  int r0 = atomicAdd(&rank[e0], 1);
  int p0 = base[e0] + r0;
  pair_tok[p0] = t; pair_w[p0] = w0; pair_slot[t * 2] = p0;
  int r1 = atomicAdd(&rank[e1], 1);
  int p1 = base[e1] + r1;
  pair_tok[p1] = t; pair_w[p1] = w1; pair_slot[t * 2 + 1] = p1;
}

// ---------------- fused 2-layer expert MLP v11: R8 geometry (128 pairs, 8 waves
// 4mg x 2ng, M=32/wave) + ONE barrier/chunk via A||B software pipeline:
// iter c = { stage(c+1); B(c-1); A(c); barrier }. B(c-1) and A(c) are
// independent (disjoint buffers) -> compiler interleaves their MFMA chains.
// w1s dbuf, w2s TRIPLE-buf (stage c+1 vs read c-1: distinct mod 3), hs dbuf.
// 98KB LDS -> 1 block/CU (measured best regime); regs = R8's proven 96+64.
__global__ __launch_bounds__(512, 1) void moe_gemm_kernel(
    const unsigned short* __restrict__ x_bf,   // [B][256]
    const unsigned short* __restrict__ W1t,    // [E][512 h][256 i]
    const unsigned short* __restrict__ W2c,    // [E][16 c][256 o][32 h]
    const float* __restrict__ b1,              // [E][512]
    const float* __restrict__ b2,              // [E][256]
    const int* __restrict__ pair_tok, const float* __restrict__ pair_w,
    const int* __restrict__ bm_e, const int* __restrict__ bm_start,
    const int* __restrict__ bm_end,
    unsigned short* __restrict__ ypair){       // [65536][256] bf16
  int xcd = blockIdx.x & 7, slot = blockIdx.x >> 3;
  int bmi = xcd * SLOTS + slot;
  int e = bm_e[bmi];
  if (e < 0) return;
  int rs = bm_start[bmi], re = bm_end[bmi];

  __shared__ unsigned short w1s[2][CH * 256];   // 2x16KB [h row][i], 512B rows, XOR
  __shared__ unsigned short w2s[3][256 * CH];   // 3x16KB [o row][h], row-pair 128B XOR
  __shared__ unsigned short hs[2][BM * CH];     // 2x8KB [m 128][h 32], row-pair XOR
  __shared__ float b1s[DHID];                   // 2KB

  int tid = threadIdx.x, wid = tid >> 6, lane = tid & 63, lr = lane & 15, lh = lane >> 4;
  int mg = wid >> 1, ng = wid & 1;
  const char* gW1 = (const char*)(W1t + (size_t)e * DHID * DIN);
  const char* gW2 = (const char*)(W2c + (size_t)e * DOUT * DHID);

  b1s[tid] = b1[e * DHID + tid];

  // per-lane staging source offsets (pre-swizzled; +8192 shift is exact for
  // the 2nd granule since bit-9 of the granule index doesn't enter the XOR)
  int o1 = ((tid >> 5) * 512) + (((tid & 31) ^ ((tid >> 5) & 7)) * 16);
  int o2;
  { int p = tid >> 3, q = (tid & 7) ^ (p & 7);
    o2 = (p * 2 + (q >> 2)) * 64 + (q & 3) * 16; }

#define STAGE_W1(c, sl) {                                                 \
    const char* s1 = gW1 + (size_t)(c) * 16384;                           \
    char* d1 = (char*)w1s[sl];                                            \
    gload16(s1 + o1,        d1 + tid * 16);                               \
    gload16(s1 + o1 + 8192, d1 + tid * 16 + 8192);                        \
  }
#define STAGE_W2(c, sl) {                                                 \
    const char* s2 = gW2 + (size_t)(c) * 16384;                           \
    char* d2 = (char*)w2s[sl];                                            \
    gload16(s2 + o2,        d2 + tid * 16);                               \
    gload16(s2 + o2 + 8192, d2 + tid * 16 + 8192);                        \
  }

  // ---- x rows (2 m-tiles of this wave's 32-token band) -> registers
  bf16x8 xr[2][8];
#pragma unroll
  for (int m = 0; m < 2; m++){
    int g0 = rs + 32 * mg + m * 16 + lr;
    int gc = g0 < re ? g0 : (re - 1);
    int tok = pair_tok[gc];
    const unsigned short* xrow = x_bf + (size_t)tok * DIN + lh * 8;
#pragma unroll
    for (int ks = 0; ks < 8; ks++) xr[m][ks] = *(const bf16x8*)(xrow + ks * 32);
  }

  f32x4 acc[2][8];
#pragma unroll
  for (int m = 0; m < 2; m++)
#pragma unroll
    for (int i = 0; i < 8; i++) acc[m][i] = (f32x4){0.f, 0.f, 0.f, 0.f};

  STAGE_W1(0, 0); STAGE_W2(0, 0);
  __syncthreads();                       // chunk-0 staged; b1s ready

  for (int c = 0; c < NCH; c++){
    if (c + 1 < NCH){ STAGE_W1(c + 1, (c + 1) & 1); STAGE_W2(c + 1, (c + 1) % 3); }

    // ---- phase B of chunk c-1 (independent of phase A below)
    if (c > 0){
      int pc = c - 1;
      const char* hpb = (const char*)hs[pc & 1];
      const char* w2b = (const char*)w2s[pc % 3];
      bf16x8 ha[2];
#pragma unroll
      for (int m = 0; m < 2; m++){
        int mm = 32 * mg + m * 16 + lr;
        int hadr = (mm >> 1) * 128 + ((((mm & 1) << 6) + (lh << 4)) ^ (((mm >> 1) & 7) << 4));
        ha[m] = *(const bf16x8*)(hpb + hadr);
      }
#pragma unroll
      for (int nt = 0; nt < 8; nt++){
        int n = 128 * ng + nt * 16 + lr;
        int adr = (n >> 1) * 128 + ((((n & 1) << 6) + (lh << 4)) ^ (((n >> 1) & 7) << 4));
        bf16x8 b = *(const bf16x8*)(w2b + adr);
        acc[0][nt] = __builtin_amdgcn_mfma_f32_16x16x32_bf16(ha[0], b, acc[0][nt], 0, 0, 0);
        acc[1][nt] = __builtin_amdgcn_mfma_f32_16x16x32_bf16(ha[1], b, acc[1][nt], 0, 0, 0);
      }
    }

    // ---- phase A of chunk c: h[128 tok][16 hid of ng] = x @ W1c
    {
      const char* w1b = (const char*)w1s[c & 1];
      f32x4 hacc[2];
      hacc[0] = (f32x4){0.f, 0.f, 0.f, 0.f};
      hacc[1] = (f32x4){0.f, 0.f, 0.f, 0.f};
      int hrow = 16 * ng + lr;
#pragma unroll
      for (int ks = 0; ks < 8; ks++){
        bf16x8 b = *(const bf16x8*)(w1b + ((hrow * 512 + ks * 64 + lh * 16) ^ ((hrow & 7) << 4)));
        hacc[0] = __builtin_amdgcn_mfma_f32_16x16x32_bf16(xr[0][ks], b, hacc[0], 0, 0, 0);
        hacc[1] = __builtin_amdgcn_mfma_f32_16x16x32_bf16(xr[1][ks], b, hacc[1], 0, 0, 0);
      }
      // relu(h+b1) -> hs[c&1] (row-pair XOR layout)
      char* hwb = (char*)hs[c & 1];
      float b1v = b1s[c * CH + 16 * ng + lr];
      int col2 = (16 * ng + lr) * 2;
#pragma unroll
      for (int m = 0; m < 2; m++)
#pragma unroll
        for (int r = 0; r < 4; r++){
          int mm = 32 * mg + m * 16 + lh * 4 + r;
          float v = fmaxf(hacc[m][r] + b1v, 0.f);
          int adr = (mm >> 1) * 128 + ((((mm & 1) << 6) + col2) ^ (((mm >> 1) & 7) << 4));
          *(unsigned short*)(hwb + adr) = f2bf(v);
        }
    }
    __syncthreads();   // publishes hs[c&1]; drains stage(c+1); frees read slots
  }

  // ---- final phase B (chunk NCH-1)
  {
    int pc = NCH - 1;
    const char* hpb = (const char*)hs[pc & 1];
    const char* w2b = (const char*)w2s[pc % 3];
    bf16x8 ha[2];
#pragma unroll
    for (int m = 0; m < 2; m++){
      int mm = 32 * mg + m * 16 + lr;
      int hadr = (mm >> 1) * 128 + ((((mm & 1) << 6) + (lh << 4)) ^ (((mm >> 1) & 7) << 4));
      ha[m] = *(const bf16x8*)(hpb + hadr);
    }
#pragma unroll
    for (int nt = 0; nt < 8; nt++){
      int n = 128 * ng + nt * 16 + lr;
      int adr = (n >> 1) * 128 + ((((n & 1) << 6) + (lh << 4)) ^ (((n >> 1) & 7) << 4));
      bf16x8 b = *(const bf16x8*)(w2b + adr);
      acc[0][nt] = __builtin_amdgcn_mfma_f32_16x16x32_bf16(ha[0], b, acc[0][nt], 0, 0, 0);
      acc[1][nt] = __builtin_amdgcn_mfma_f32_16x16x32_bf16(ha[1], b, acc[1][nt], 0, 0, 0);
    }
  }

  // ---- epilogue: fold gate weight + b2, store per-pair bf16 rows
#pragma unroll
  for (int m = 0; m < 2; m++){
    float wrow[4]; int grow[4];
#pragma unroll
    for (int r = 0; r < 4; r++){
      int gg = rs + 32 * mg + m * 16 + lh * 4 + r;
      grow[r] = gg;
      wrow[r] = (gg < re) ? pair_w[gg] : 0.f;
    }
#pragma unroll
    for (int nt = 0; nt < 8; nt++){
      int col = 128 * ng + nt * 16 + lr;
      float b2v = b2[e * DOUT + col];
#pragma unroll
      for (int r = 0; r < 4; r++){
        if (grow[r] < re)
          ypair[(size_t)grow[r] * DOUT + col] = f2bf(wrow[r] * (acc[m][nt][r] + b2v));
      }
    }
  }
#undef STAGE_W1
#undef STAGE_W2
}

// ---------------- combine two pair rows per token
__global__ __launch_bounds__(256) void combine_kernel(const unsigned short* __restrict__ yp,
                                                      const int* __restrict__ pair_slot,
                                                      float* __restrict__ out){
  int idx = blockIdx.x * 256 + threadIdx.x;
  int t = idx >> 6;
  int c4 = (idx & 63) << 2;
  int s0 = pair_slot[t * 2], s1 = pair_slot[t * 2 + 1];
  ushort4 a = *(const ushort4*)(yp + (size_t)s0 * DOUT + c4);
  ushort4 b = *(const ushort4*)(yp + (size_t)s1 * DOUT + c4);
  float4 o;
  o.x = bf2f(a.x) + bf2f(b.x);
  o.y = bf2f(a.y) + bf2f(b.y);
  o.z = bf2f(a.z) + bf2f(b.z);
  o.w = bf2f(a.w) + bf2f(b.w);
  *(float4*)(out + (size_t)t * DOUT + c4) = o;
}

extern "C" void kernel_launch(void* const* d_in, const int* in_sizes, int n_in,
                              void* d_out, int out_size, void* d_ws, size_t ws_size,
                              hipStream_t stream){
  (void)in_sizes; (void)n_in; (void)out_size; (void)ws_size;
  const float* x  = (const float*)d_in[0];
  const float* Wg = (const float*)d_in[1];
  const float* bg = (const float*)d_in[2];
  const float* W1 = (const float*)d_in[3];
  const float* b1 = (const float*)d_in[4];
  const float* W2 = (const float*)d_in[5];
  const float* b2 = (const float*)d_in[6];
  float* out = (float*)d_out;
  char* ws = (char*)d_ws;

  unsigned short* x_bf  = (unsigned short*)(ws);                 // 16,777,216
  unsigned short* W1t   = (unsigned short*)(ws + 16777216);      //  4,194,304
  unsigned short* W2ck  = (unsigned short*)(ws + 20971520);      //  4,194,304
  unsigned short* ypair = (unsigned short*)(ws + 25165824);      // 33,554,432
  int*   top_idx  = (int*)  (ws + 58720256);
  float* top_w    = (float*)(ws + 58982400);
  int*   pair_tok = (int*)  (ws + 59244544);
  float* pair_w   = (float*)(ws + 59506688);
  int*   pair_slot= (int*)  (ws + 59768832);
  int*   counts   = (int*)  (ws + 60030976);
  int*   offsets  = (int*)  (ws + 60031040);
  int*   cursor   = (int*)  (ws + 60031104);
  int*   bm_e     = (int*)  (ws + 60031232);   // 768 ints
  int*   bm_start = (int*)  (ws + 60036608);   // 768 ints
  int*   bm_end   = (int*)  (ws + 60041984);   // 768 ints

  hipMemsetAsync(counts, 0, 64, stream);
  prep_kernel<<<4608, 256, 0, stream>>>(x, Wg, bg, W1, W2, W1t, W2ck,
                                        x_bf, top_idx, top_w, counts);
  prefix_kernel<<<1, 64, 0, stream>>>(counts, offsets, cursor, bm_e, bm_start, bm_end);
  scatter_kernel<<<128, 256, 0, stream>>>(top_idx, top_w, cursor, pair_tok, pair_w, pair_slot);
  moe_gemm_kernel<<<8 * SLOTS, 512, 0, stream>>>(x_bf, W1t, W2ck, b1, b2, pair_tok, pair_w,
                                                 bm_e, bm_start, bm_end, ypair);
  combine_kernel<<<8192, 256, 0, stream>>>(ypair, pair_slot, out);
}

// Round 12
// 202.731 us; speedup vs baseline: 1.4229x; 1.0626x over previous
//
#include <hip/hip_runtime.h>
#include <stdint.h>

#define BTOK 32768
#define DIN 256
#define DHID 512
#define DOUT 256
#define NEXP 16
#define BM 64
#define SLOTS 168

typedef __attribute__((ext_vector_type(8))) short bf16x8;
typedef __attribute__((ext_vector_type(4))) float f32x4;

__device__ __forceinline__ unsigned short f2bf(float f){
  unsigned u = __builtin_bit_cast(unsigned, f);
  u = u + 0x7FFFu + ((u >> 16) & 1u);      // RNE, finite inputs only
  return (unsigned short)(u >> 16);
}
__device__ __forceinline__ float bf2f(unsigned short h){
  return __builtin_bit_cast(float, (unsigned)h << 16);
}
__device__ __forceinline__ void gload16(const void* g, void* l){
  __builtin_amdgcn_global_load_lds((const __attribute__((address_space(1))) unsigned int*)g,
                                   (__attribute__((address_space(3))) unsigned int*)l, 16, 0, 0);
}

// ---------------- transpose + f32->bf16 convert:  src[e][R][C] -> dst[e][C][R]
__global__ __launch_bounds__(256) void transpose_cvt(const float* __restrict__ src,
                                                     unsigned short* __restrict__ dst,
                                                     int R, int C){
  __shared__ float t[32][33];
  int e = blockIdx.z, r0 = blockIdx.y * 32, c0 = blockIdx.x * 32;
  int lx = threadIdx.x & 31, ly = threadIdx.x >> 5;
  const float* s = src + (size_t)e * R * C;
  unsigned short* d = dst + (size_t)e * R * C;
#pragma unroll
  for (int i = 0; i < 4; i++){ int r = ly + i * 8; t[r][lx] = s[(size_t)(r0 + r) * C + c0 + lx]; }
  __syncthreads();
#pragma unroll
  for (int i = 0; i < 4; i++){ int r = ly + i * 8; d[(size_t)(c0 + r) * R + r0 + lx] = f2bf(t[lx][r]); }
}

// ---------------- gating: 512 blocks x 64 tokens; LDS-aggregated histogram
__global__ __launch_bounds__(256) void gating_kernel(const float* __restrict__ x,
                                                     const float* __restrict__ Wg,
                                                     const float* __restrict__ bg,
                                                     unsigned short* __restrict__ x_bf,
                                                     int* __restrict__ top_idx,
                                                     float* __restrict__ top_w,
                                                     int* __restrict__ counts){
  __shared__ float WgT[16][256];
  __shared__ int hist[16];
  int tid = threadIdx.x;
#pragma unroll
  for (int j = 0; j < 4; j++){
    float4 wv = *(const float4*)(Wg + tid * 16 + j * 4);
    WgT[j * 4 + 0][tid] = wv.x; WgT[j * 4 + 1][tid] = wv.y;
    WgT[j * 4 + 2][tid] = wv.z; WgT[j * 4 + 3][tid] = wv.w;
  }
  if (tid < 16) hist[tid] = 0;
  __syncthreads();
  int wid = tid >> 6, lane = tid & 63;

  for (int t = 0; t < 16; t++){
    int tok = blockIdx.x * 64 + wid * 16 + t;
    const float4 xv = *(const float4*)(x + (size_t)tok * DIN + lane * 4);
    ushort4 xb; xb.x = f2bf(xv.x); xb.y = f2bf(xv.y); xb.z = f2bf(xv.z); xb.w = f2bf(xv.w);
    *(ushort4*)(x_bf + (size_t)tok * DIN + lane * 4) = xb;
    float logit[16];
#pragma unroll
    for (int e = 0; e < 16; e++){
      const float4 wv = *(const float4*)(&WgT[e][lane * 4]);
      float v = xv.x * wv.x + xv.y * wv.y + xv.z * wv.z + xv.w * wv.w;
#pragma unroll
      for (int off = 32; off; off >>= 1) v += __shfl_xor(v, off, 64);
      logit[e] = v + bg[e];
    }
    if (lane == 0){
      int i1 = 0; float v1 = logit[0];
#pragma unroll
      for (int e = 1; e < 16; e++) if (logit[e] > v1){ v1 = logit[e]; i1 = e; }
      int i2 = -1; float v2 = -3.4e38f;
#pragma unroll
      for (int e = 0; e < 16; e++) if (e != i1 && logit[e] > v2){ v2 = logit[e]; i2 = e; }
      float tt = expf(v2 - v1);
      float w1 = 1.0f / (1.0f + tt);
      float w2 = tt / (1.0f + tt);
      top_idx[tok * 2] = i1; top_idx[tok * 2 + 1] = i2;
      top_w[tok * 2] = w1;  top_w[tok * 2 + 1] = w2;
      atomicAdd(&hist[i1], 1); atomicAdd(&hist[i2], 1);
    }
  }
  __syncthreads();
  if (tid < 16) atomicAdd(&counts[tid], hist[tid]);
}

// ---------------- prefix sum + XCD-affine block map (one wave)
__global__ void prefix_kernel(const int* __restrict__ counts, int* __restrict__ offsets,
                              int* __restrict__ cursor, int* __restrict__ bm_e,
                              int* __restrict__ bm_start, int* __restrict__ bm_end){
  int lane = threadIdx.x & 63;
  int c = (lane < 16) ? counts[lane] : 0;
  int s = c;
#pragma unroll
  for (int off = 1; off < 16; off <<= 1){ int o = __shfl_up(s, off, 64); if (lane >= off) s += o; }
  int start = s - c;
  if (lane < 16){ offsets[lane] = start; cursor[lane] = start; }
  int nb = (c + BM - 1) >> 6;
  int nb_partner = __shfl(nb, lane ^ 8, 64);
  if (lane < 8){
    int filled = nb + nb_partner;
    if (filled > SLOTS) filled = SLOTS;
    for (int i = filled; i < SLOTS; i++) bm_e[lane * SLOTS + i] = -1;
  }
  if (lane < 16){
    int sbase = (lane < 8) ? 0 : nb_partner;
    int xcd = lane & 7;
    for (int b = 0; b < nb; b++){
      int idx = xcd * SLOTS + sbase + b;
      if (sbase + b < SLOTS){
        bm_e[idx] = lane; bm_start[idx] = start + b * BM; bm_end[idx] = start + c;
      }
    }
  }
}

// ---------------- scatter: block-aggregated chunk reservation, LDS ranks
__global__ __launch_bounds__(256) void scatter_kernel(const int* __restrict__ top_idx,
                                                      const float* __restrict__ top_w,
                                                      int* __restrict__ cursor,
                                                      int* __restrict__ pair_tok,
                                                      float* __restrict__ pair_w,
                                                      int* __restrict__ pair_slot){
  __shared__ int hist[16], base[16], rank[16];
  int tid = threadIdx.x;
  if (tid < 16){ hist[tid] = 0; rank[tid] = 0; }
  __syncthreads();
  int t = blockIdx.x * 256 + tid;
  int e0 = top_idx[t * 2], e1 = top_idx[t * 2 + 1];
  float w0 = top_w[t * 2], w1 = top_w[t * 2 + 1];
  atomicAdd(&hist[e0], 1); atomicAdd(&hist[e1], 1);
  __syncthreads();
  if (tid < 16) base[tid] = atomicAdd(&cursor[tid], hist[tid]);
  __syncthreads();
  int r0 = atomicAdd(&rank[e0], 1);
  int p0 = base[e0] + r0;
  pair_tok[p0] = t; pair_w[p0] = w0; pair_slot[t * 2] = p0;
  int r1 = atomicAdd(&rank[e1], 1);
  int p1 = base[e1] + r1;
  pair_tok[p1] = t; pair_w[p1] = w1; pair_slot[t * 2 + 1] = p1;
}

// ---------------- fused 2-layer expert MLP v12: WEIGHT-STATIONARY waves.
// 64 pairs/block, 8 waves. W1/W2 fragments live in REGISTERS (loaded from
// XCD-local L2 once per block + one half-switch reload) -- zero W LDS traffic.
// x staged once (32KB); h through LDS in 2 hid-halves (32KB). 4 barriers total.
// Wave roles: hid-slice = wid*32 (phase A), out cols wid*16 & 128+wid*16 (B).
__global__ __launch_bounds__(512, 2) void moe_gemm_kernel(
    const unsigned short* __restrict__ x_bf,   // [B][256]
    const unsigned short* __restrict__ W1t,    // [E][512 h][256 i]
    const unsigned short* __restrict__ W2t,    // [E][256 o][512 h]
    const float* __restrict__ b1,              // [E][512]
    const float* __restrict__ b2,              // [E][256]
    const int* __restrict__ pair_tok, const float* __restrict__ pair_w,
    const int* __restrict__ bm_e, const int* __restrict__ bm_start,
    const int* __restrict__ bm_end,
    unsigned short* __restrict__ ypair){       // [65536][256] bf16
  int xcd = blockIdx.x & 7, slot = blockIdx.x >> 3;
  int bmi = xcd * SLOTS + slot;
  int e = bm_e[bmi];
  if (e < 0) return;
  int rs = bm_start[bmi], re = bm_end[bmi];

  __shared__ unsigned short xs[BM * 256];   // 32KB, 512B rows, XOR(t&15) swizzle
  __shared__ unsigned short hsm[BM * 256];  // 32KB (one 256-hid half), same layout
  char* xsb = (char*)xs; char* hsb = (char*)hsm;

  int tid = threadIdx.x, wid = tid >> 6, lane = tid & 63, lr = lane & 15, lh = lane >> 4;
  const unsigned short* W1e = W1t + (size_t)e * DHID * DIN;
  const unsigned short* W2e = W2t + (size_t)e * DOUT * DHID;

  // ---- stage x tile (64 rows x 512B), linear LDS dest + pre-swizzled source
#pragma unroll
  for (int k = 0; k < 4; k++){
    int g = k * 512 + tid;
    int row = g >> 5, cg = g & 31;
    int gg = rs + row; int gc = gg < re ? gg : re - 1;
    int tok = pair_tok[gc];
    gload16((const char*)(x_bf + (size_t)tok * DIN) + ((cg ^ (row & 15)) * 16),
            xsb + g * 16);
  }

  // ---- W1 fragments, hid half 0: wave slice = rows wid*32 .. +31
  bf16x8 w1f[2][8];
#pragma unroll
  for (int nt = 0; nt < 2; nt++)
#pragma unroll
    for (int ks = 0; ks < 8; ks++)
      w1f[nt][ks] = *(const bf16x8*)(W1e + (size_t)(wid * 32 + nt * 16 + lr) * DIN + ks * 32 + lh * 8);
  // ---- W2 fragments, k half 0: out rows {wid*16, 128+wid*16}
  bf16x8 w2f[2][8];
#pragma unroll
  for (int o = 0; o < 2; o++)
#pragma unroll
    for (int ks = 0; ks < 8; ks++)
      w2f[o][ks] = *(const bf16x8*)(W2e + (size_t)(o * 128 + wid * 16 + lr) * DHID + ks * 32 + lh * 8);

  f32x4 acc[2][4];
#pragma unroll
  for (int o = 0; o < 2; o++)
#pragma unroll
    for (int s = 0; s < 4; s++) acc[o][s] = (f32x4){0.f, 0.f, 0.f, 0.f};

  __syncthreads();                         // xs staged

#pragma unroll
  for (int p = 0; p < 2; p++){
    // ---- phase A: h[64 tok][hid half p] ; B-operand from registers
    float b1v0 = b1[e * DHID + p * 256 + wid * 32 + lr];
    float b1v1 = b1[e * DHID + p * 256 + wid * 32 + 16 + lr];
#pragma unroll
    for (int sub = 0; sub < 4; sub++){
      f32x4 h0 = (f32x4){0.f, 0.f, 0.f, 0.f};
      f32x4 h1 = (f32x4){0.f, 0.f, 0.f, 0.f};
      int ta = sub * 16 + lr;
#pragma unroll
      for (int ks = 0; ks < 8; ks++){
        bf16x8 a = *(const bf16x8*)(xsb + ta * 512 + ((ks * 64 + lh * 16) ^ ((ta & 15) << 4)));
        h0 = __builtin_amdgcn_mfma_f32_16x16x32_bf16(a, w1f[0][ks], h0, 0, 0, 0);
        h1 = __builtin_amdgcn_mfma_f32_16x16x32_bf16(a, w1f[1][ks], h1, 0, 0, 0);
      }
      int c0 = (wid * 32 + lr) * 2;
      int c1 = (wid * 32 + 16 + lr) * 2;
#pragma unroll
      for (int r = 0; r < 4; r++){
        int t = sub * 16 + lh * 4 + r;
        int swz = (t & 15) << 4;
        *(unsigned short*)(hsb + t * 512 + (c0 ^ swz)) = f2bf(fmaxf(h0[r] + b1v0, 0.f));
        *(unsigned short*)(hsb + t * 512 + (c1 ^ swz)) = f2bf(fmaxf(h1[r] + b1v1, 0.f));
      }
    }
    if (p == 0){                           // preload W1 half 1 (w1f dead until A(p1))
#pragma unroll
      for (int nt = 0; nt < 2; nt++)
#pragma unroll
        for (int ks = 0; ks < 8; ks++)
          w1f[nt][ks] = *(const bf16x8*)(W1e + (size_t)(256 + wid * 32 + nt * 16 + lr) * DIN + ks * 32 + lh * 8);
    }
    __syncthreads();                       // hs(p) published

    // ---- phase B: y += h(half p) @ W2(k half p) ; B-operand from registers
#pragma unroll
    for (int sub = 0; sub < 4; sub++){
      int tb = sub * 16 + lr;
#pragma unroll
      for (int ks = 0; ks < 8; ks++){
        bf16x8 ha = *(const bf16x8*)(hsb + tb * 512 + ((ks * 64 + lh * 16) ^ ((tb & 15) << 4)));
        acc[0][sub] = __builtin_amdgcn_mfma_f32_16x16x32_bf16(ha, w2f[0][ks], acc[0][sub], 0, 0, 0);
        acc[1][sub] = __builtin_amdgcn_mfma_f32_16x16x32_bf16(ha, w2f[1][ks], acc[1][sub], 0, 0, 0);
      }
    }
    if (p == 0){                           // reload W2 for k half 1
#pragma unroll
      for (int o = 0; o < 2; o++)
#pragma unroll
        for (int ks = 0; ks < 8; ks++)
          w2f[o][ks] = *(const bf16x8*)(W2e + (size_t)(o * 128 + wid * 16 + lr) * DHID + 256 + ks * 32 + lh * 8);
      __syncthreads();                     // hs free before A(p1) overwrites
    }
  }

  // ---- epilogue: fold gate weight + b2, store per-pair bf16 rows
#pragma unroll
  for (int o = 0; o < 2; o++){
    int col = o * 128 + wid * 16 + lr;
    float b2v = b2[e * DOUT + col];
#pragma unroll
    for (int sub = 0; sub < 4; sub++){
#pragma unroll
      for (int r = 0; r < 4; r++){
        int t = sub * 16 + lh * 4 + r;
        int gg = rs + t;
        if (gg < re){
          float w = pair_w[gg];
          ypair[(size_t)gg * DOUT + col] = f2bf(w * (acc[o][sub][r] + b2v));
        }
      }
    }
  }
}

// ---------------- combine two pair rows per token
__global__ __launch_bounds__(256) void combine_kernel(const unsigned short* __restrict__ yp,
                                                      const int* __restrict__ pair_slot,
                                                      float* __restrict__ out){
  int idx = blockIdx.x * 256 + threadIdx.x;
  int t = idx >> 6;
  int c4 = (idx & 63) << 2;
  int s0 = pair_slot[t * 2], s1 = pair_slot[t * 2 + 1];
  ushort4 a = *(const ushort4*)(yp + (size_t)s0 * DOUT + c4);
  ushort4 b = *(const ushort4*)(yp + (size_t)s1 * DOUT + c4);
  float4 o;
  o.x = bf2f(a.x) + bf2f(b.x);
  o.y = bf2f(a.y) + bf2f(b.y);
  o.z = bf2f(a.z) + bf2f(b.z);
  o.w = bf2f(a.w) + bf2f(b.w);
  *(float4*)(out + (size_t)t * DOUT + c4) = o;
}

extern "C" void kernel_launch(void* const* d_in, const int* in_sizes, int n_in,
                              void* d_out, int out_size, void* d_ws, size_t ws_size,
                              hipStream_t stream){
  (void)in_sizes; (void)n_in; (void)out_size; (void)ws_size;
  const float* x  = (const float*)d_in[0];
  const float* Wg = (const float*)d_in[1];
  const float* bg = (const float*)d_in[2];
  const float* W1 = (const float*)d_in[3];
  const float* b1 = (const float*)d_in[4];
  const float* W2 = (const float*)d_in[5];
  const float* b2 = (const float*)d_in[6];
  float* out = (float*)d_out;
  char* ws = (char*)d_ws;

  unsigned short* x_bf  = (unsigned short*)(ws);                 // 16,777,216
  unsigned short* W1t   = (unsigned short*)(ws + 16777216);      //  4,194,304
  unsigned short* W2t   = (unsigned short*)(ws + 20971520);      //  4,194,304
  unsigned short* ypair = (unsigned short*)(ws + 25165824);      // 33,554,432
  int*   top_idx  = (int*)  (ws + 58720256);
  float* top_w    = (float*)(ws + 58982400);
  int*   pair_tok = (int*)  (ws + 59244544);
  float* pair_w   = (float*)(ws + 59506688);
  int*   pair_slot= (int*)  (ws + 59768832);
  int*   counts   = (int*)  (ws + 60030976);
  int*   offsets  = (int*)  (ws + 60031040);
  int*   cursor   = (int*)  (ws + 60031104);
  int*   bm_e     = (int*)  (ws + 60031232);   // 1344 ints
  int*   bm_start = (int*)  (ws + 60036608);   // 1344 ints
  int*   bm_end   = (int*)  (ws + 60041984);   // 1344 ints

  hipMemsetAsync(counts, 0, 64, stream);
  transpose_cvt<<<dim3(16, 8, 16), 256, 0, stream>>>(W1, W1t, 256, 512);
  transpose_cvt<<<dim3(8, 16, 16), 256, 0, stream>>>(W2, W2t, 512, 256);
  gating_kernel<<<512, 256, 0, stream>>>(x, Wg, bg, x_bf, top_idx, top_w, counts);
  prefix_kernel<<<1, 64, 0, stream>>>(counts, offsets, cursor, bm_e, bm_start, bm_end);
  scatter_kernel<<<128, 256, 0, stream>>>(top_idx, top_w, cursor, pair_tok, pair_w, pair_slot);
  moe_gemm_kernel<<<8 * SLOTS, 512, 0, stream>>>(x_bf, W1t, W2t, b1, b2, pair_tok, pair_w,
                                                 bm_e, bm_start, bm_end, ypair);
  combine_kernel<<<8192, 256, 0, stream>>>(ypair, pair_slot, out);
}

// Round 13
// 174.160 us; speedup vs baseline: 1.6563x; 1.1641x over previous
//
#include <hip/hip_runtime.h>
#include <stdint.h>

#define BTOK 32768
#define DIN 256
#define DHID 512
#define DOUT 256
#define NEXP 16
#define BM 128
#define CH 32
#define NCH 16
#define SLOTS 96

typedef __attribute__((ext_vector_type(8))) short bf16x8;
typedef __attribute__((ext_vector_type(4))) float f32x4;

__device__ __forceinline__ unsigned short f2bf(float f){
  unsigned u = __builtin_bit_cast(unsigned, f);
  u = u + 0x7FFFu + ((u >> 16) & 1u);      // RNE, finite inputs only
  return (unsigned short)(u >> 16);
}
__device__ __forceinline__ float bf2f(unsigned short h){
  return __builtin_bit_cast(float, (unsigned)h << 16);
}
__device__ __forceinline__ void gload16(const void* g, void* l){
  __builtin_amdgcn_global_load_lds((const __attribute__((address_space(1))) unsigned int*)g,
                                   (__attribute__((address_space(3))) unsigned int*)l, 16, 0, 0);
}

// ---------------- W1 transpose + cvt: src[e][256 i][512 h] -> dst[e][512 h][256 i]
__global__ __launch_bounds__(256) void transpose_cvt(const float* __restrict__ src,
                                                     unsigned short* __restrict__ dst,
                                                     int R, int C){
  __shared__ float t[32][33];
  int e = blockIdx.z, r0 = blockIdx.y * 32, c0 = blockIdx.x * 32;
  int lx = threadIdx.x & 31, ly = threadIdx.x >> 5;
  const float* s = src + (size_t)e * R * C;
  unsigned short* d = dst + (size_t)e * R * C;
#pragma unroll
  for (int i = 0; i < 4; i++){ int r = ly + i * 8; t[r][lx] = s[(size_t)(r0 + r) * C + c0 + lx]; }
  __syncthreads();
#pragma unroll
  for (int i = 0; i < 4; i++){ int r = ly + i * 8; d[(size_t)(c0 + r) * R + r0 + lx] = f2bf(t[lx][r]); }
}

// ---------------- W2 transpose + cvt into chunk-major: src[e][512 h][256 o] -> dst[e][16][256 o][32 h]
__global__ __launch_bounds__(256) void transpose_cvt_w2(const float* __restrict__ src,
                                                        unsigned short* __restrict__ dst){
  __shared__ float t[32][33];
  int e = blockIdx.z, r0 = blockIdx.y * 32, c0 = blockIdx.x * 32;   // r0 over h, c0 over o
  int lx = threadIdx.x & 31, ly = threadIdx.x >> 5;
  const float* s = src + (size_t)e * DHID * DOUT;
  unsigned short* d = dst + (size_t)e * DHID * DOUT + (r0 >> 5) * (DOUT * CH);
#pragma unroll
  for (int i = 0; i < 4; i++){ int r = ly + i * 8; t[r][lx] = s[(size_t)(r0 + r) * DOUT + c0 + lx]; }
  __syncthreads();
#pragma unroll
  for (int i = 0; i < 4; i++){ int rr = ly + i * 8; d[(size_t)(c0 + rr) * CH + lx] = f2bf(t[lx][rr]); }
}

// ---------------- gating: 512 blocks x 64 tokens; LDS-aggregated histogram
__global__ __launch_bounds__(256) void gating_kernel(const float* __restrict__ x,
                                                     const float* __restrict__ Wg,
                                                     const float* __restrict__ bg,
                                                     unsigned short* __restrict__ x_bf,
                                                     int* __restrict__ top_idx,
                                                     float* __restrict__ top_w,
                                                     int* __restrict__ counts){
  __shared__ float WgT[16][256];
  __shared__ int hist[16];
  int tid = threadIdx.x;
#pragma unroll
  for (int j = 0; j < 4; j++){
    float4 wv = *(const float4*)(Wg + tid * 16 + j * 4);
    WgT[j * 4 + 0][tid] = wv.x; WgT[j * 4 + 1][tid] = wv.y;
    WgT[j * 4 + 2][tid] = wv.z; WgT[j * 4 + 3][tid] = wv.w;
  }
  if (tid < 16) hist[tid] = 0;
  __syncthreads();
  int wid = tid >> 6, lane = tid & 63;

  for (int t = 0; t < 16; t++){
    int tok = blockIdx.x * 64 + wid * 16 + t;
    const float4 xv = *(const float4*)(x + (size_t)tok * DIN + lane * 4);
    ushort4 xb; xb.x = f2bf(xv.x); xb.y = f2bf(xv.y); xb.z = f2bf(xv.z); xb.w = f2bf(xv.w);
    *(ushort4*)(x_bf + (size_t)tok * DIN + lane * 4) = xb;
    float logit[16];
#pragma unroll
    for (int e = 0; e < 16; e++){
      const float4 wv = *(const float4*)(&WgT[e][lane * 4]);
      float v = xv.x * wv.x + xv.y * wv.y + xv.z * wv.z + xv.w * wv.w;
#pragma unroll
      for (int off = 32; off; off >>= 1) v += __shfl_xor(v, off, 64);
      logit[e] = v + bg[e];
    }
    if (lane == 0){
      int i1 = 0; float v1 = logit[0];
#pragma unroll
      for (int e = 1; e < 16; e++) if (logit[e] > v1){ v1 = logit[e]; i1 = e; }
      int i2 = -1; float v2 = -3.4e38f;
#pragma unroll
      for (int e = 0; e < 16; e++) if (e != i1 && logit[e] > v2){ v2 = logit[e]; i2 = e; }
      float tt = expf(v2 - v1);
      float w1 = 1.0f / (1.0f + tt);
      float w2 = tt / (1.0f + tt);
      top_idx[tok * 2] = i1; top_idx[tok * 2 + 1] = i2;
      top_w[tok * 2] = w1;  top_w[tok * 2 + 1] = w2;
      atomicAdd(&hist[i1], 1); atomicAdd(&hist[i2], 1);
    }
  }
  __syncthreads();
  if (tid < 16) atomicAdd(&counts[tid], hist[tid]);
}

// ---------------- prefix sum + XCD-affine block map (one wave)
__global__ void prefix_kernel(const int* __restrict__ counts, int* __restrict__ offsets,
                              int* __restrict__ cursor, int* __restrict__ bm_e,
                              int* __restrict__ bm_start, int* __restrict__ bm_end){
  int lane = threadIdx.x & 63;
  int c = (lane < 16) ? counts[lane] : 0;
  int s = c;
#pragma unroll
  for (int off = 1; off < 16; off <<= 1){ int o = __shfl_up(s, off, 64); if (lane >= off) s += o; }
  int start = s - c;
  if (lane < 16){ offsets[lane] = start; cursor[lane] = start; }
  int nb = (c + BM - 1) >> 7;
  int nb_partner = __shfl(nb, lane ^ 8, 64);
  if (lane < 8){
    int filled = nb + nb_partner;
    if (filled > SLOTS) filled = SLOTS;
    for (int i = filled; i < SLOTS; i++) bm_e[lane * SLOTS + i] = -1;
  }
  if (lane < 16){
    int sbase = (lane < 8) ? 0 : nb_partner;
    int xcd = lane & 7;
    for (int b = 0; b < nb; b++){
      int idx = xcd * SLOTS + sbase + b;
      if (sbase + b < SLOTS){
        bm_e[idx] = lane; bm_start[idx] = start + b * BM; bm_end[idx] = start + c;
      }
    }
  }
}

// ---------------- scatter: block-aggregated chunk reservation, LDS ranks
// pair_tok packs token | (k << 16) so the gemm can write token-major ypair.
__global__ __launch_bounds__(256) void scatter_kernel(const int* __restrict__ top_idx,
                                                      const float* __restrict__ top_w,
                                                      int* __restrict__ cursor,
                                                      int* __restrict__ pair_tok,
                                                      float* __restrict__ pair_w){
  __shared__ int hist[16], base[16], rank[16];
  int tid = threadIdx.x;
  if (tid < 16){ hist[tid] = 0; rank[tid] = 0; }
  __syncthreads();
  int t = blockIdx.x * 256 + tid;
  int e0 = top_idx[t * 2], e1 = top_idx[t * 2 + 1];
  float w0 = top_w[t * 2], w1 = top_w[t * 2 + 1];
  atomicAdd(&hist[e0], 1); atomicAdd(&hist[e1], 1);
  __syncthreads();
  if (tid < 16) base[tid] = atomicAdd(&cursor[tid], hist[tid]);
  __syncthreads();
  int r0 = atomicAdd(&rank[e0], 1);
  int p0 = base[e0] + r0;
  pair_tok[p0] = t; pair_w[p0] = w0;
  int r1 = atomicAdd(&rank[e1], 1);
  int p1 = base[e1] + r1;
  pair_tok[p1] = t | (1 << 16); pair_w[p1] = w1;
}

// ---------------- fused 2-layer expert MLP v13: R8 geometry + counted-vmcnt
// schedule (T3/T4). Triple-buffered W staging, STAGE issued 2 chunks ahead;
// mid barrier = lgkmcnt(0)+raw s_barrier (prefetch stays in flight); end
// barrier = vmcnt(4) (newest 4 stage loads outstanding, chunk c+1 ready).
__global__ __launch_bounds__(512, 1) void moe_gemm_kernel(
    const unsigned short* __restrict__ x_bf,   // [B][256]
    const unsigned short* __restrict__ W1t,    // [E][512 h][256 i]
    const unsigned short* __restrict__ W2c,    // [E][16 c][256 o][32 h]
    const float* __restrict__ b1,              // [E][512]
    const float* __restrict__ b2,              // [E][256]
    const int* __restrict__ pair_tok, const float* __restrict__ pair_w,
    const int* __restrict__ bm_e, const int* __restrict__ bm_start,
    const int* __restrict__ bm_end,
    unsigned short* __restrict__ ypair){       // [B*2][256] bf16, token-major
  int xcd = blockIdx.x & 7, slot = blockIdx.x >> 3;
  int bmi = xcd * SLOTS + slot;
  int e = bm_e[bmi];
  if (e < 0) return;
  int rs = bm_start[bmi], re = bm_end[bmi];

  __shared__ unsigned short w1s[3][CH * 256];   // 3x16KB [h row][i], 512B rows, XOR
  __shared__ unsigned short w2s[3][256 * CH];   // 3x16KB [o row][h], row-pair 128B XOR
  __shared__ unsigned short hs[BM * CH];        // 8KB [m 128][h 32], row-pair XOR
  __shared__ float b1s[DHID];                   // 2KB

  int tid = threadIdx.x, wid = tid >> 6, lane = tid & 63, lr = lane & 15, lh = lane >> 4;
  int mg = wid >> 1, ng = wid & 1;
  char* hsb = (char*)hs;
  const char* gW1 = (const char*)(W1t + (size_t)e * DHID * DIN);
  const char* gW2 = (const char*)(W2c + (size_t)e * DOUT * DHID);

  b1s[tid] = b1[e * DHID + tid];

  // per-lane staging source offsets (pre-swizzled; +8192 keeps XOR row bits)
  int o1 = ((tid >> 5) * 512) + (((tid & 31) ^ ((tid >> 5) & 7)) * 16);
  int o2;
  { int p = tid >> 3, q = (tid & 7) ^ (p & 7);
    o2 = (p * 2 + (q >> 2)) * 64 + (q & 3) * 16; }

#define STAGE(c, sl) {                                                    \
    const char* s1 = gW1 + (size_t)(c) * 16384;                           \
    const char* s2 = gW2 + (size_t)(c) * 16384;                           \
    char* d1 = (char*)w1s[sl]; char* d2 = (char*)w2s[sl];                 \
    gload16(s1 + o1,        d1 + tid * 16);                               \
    gload16(s1 + o1 + 8192, d1 + tid * 16 + 8192);                        \
    gload16(s2 + o2,        d2 + tid * 16);                               \
    gload16(s2 + o2 + 8192, d2 + tid * 16 + 8192);                        \
  }

  // ---- x rows (2 m-tiles of this wave's 32-token band) -> registers
  bf16x8 xr[2][8];
#pragma unroll
  for (int m = 0; m < 2; m++){
    int g0 = rs + 32 * mg + m * 16 + lr;
    int gc = g0 < re ? g0 : (re - 1);
    int tok = pair_tok[gc] & 0xFFFF;
    const unsigned short* xrow = x_bf + (size_t)tok * DIN + lh * 8;
#pragma unroll
    for (int ks = 0; ks < 8; ks++) xr[m][ks] = *(const bf16x8*)(xrow + ks * 32);
  }

  f32x4 acc[2][8];
#pragma unroll
  for (int m = 0; m < 2; m++)
#pragma unroll
    for (int i = 0; i < 8; i++) acc[m][i] = (f32x4){0.f, 0.f, 0.f, 0.f};

  STAGE(0, 0); STAGE(1, 1);
  __syncthreads();                       // prologue full drain: chunks 0,1 staged

#pragma unroll 1
  for (int c = 0; c < NCH; c++){
    int b0 = c % 3;
    if (c + 2 < NCH) STAGE(c + 2, (c + 2) % 3);   // 2-ahead; stays in flight

    // ---- phase A: h[128 tok][16 hid of ng] = x @ W1c
    {
      const char* w1b = (const char*)w1s[b0];
      f32x4 hacc[2];
      hacc[0] = (f32x4){0.f, 0.f, 0.f, 0.f};
      hacc[1] = (f32x4){0.f, 0.f, 0.f, 0.f};
      int hrow = 16 * ng + lr;
#pragma unroll
      for (int ks = 0; ks < 8; ks++){
        bf16x8 b = *(const bf16x8*)(w1b + ((hrow * 512 + ks * 64 + lh * 16) ^ ((hrow & 7) << 4)));
        hacc[0] = __builtin_amdgcn_mfma_f32_16x16x32_bf16(xr[0][ks], b, hacc[0], 0, 0, 0);
        hacc[1] = __builtin_amdgcn_mfma_f32_16x16x32_bf16(xr[1][ks], b, hacc[1], 0, 0, 0);
      }
      float b1v = b1s[c * CH + 16 * ng + lr];
      int col2 = (16 * ng + lr) * 2;
#pragma unroll
      for (int m = 0; m < 2; m++)
#pragma unroll
        for (int r = 0; r < 4; r++){
          int mm = 32 * mg + m * 16 + lh * 4 + r;
          float v = fmaxf(hacc[m][r] + b1v, 0.f);
          int adr = (mm >> 1) * 128 + ((((mm & 1) << 6) + col2) ^ (((mm >> 1) & 7) << 4));
          *(unsigned short*)(hsb + adr) = f2bf(v);
        }
    }
    // ---- mid barrier: publish hs, do NOT drain vmem prefetch
    asm volatile("s_waitcnt lgkmcnt(0)" ::: "memory");
    __builtin_amdgcn_sched_barrier(0);
    __builtin_amdgcn_s_barrier();
    __builtin_amdgcn_sched_barrier(0);

    // ---- phase B: y[32 tok of mg][128 cols of ng] += h @ W2c
    {
      const char* w2b = (const char*)w2s[b0];
      bf16x8 ha[2];
#pragma unroll
      for (int m = 0; m < 2; m++){
        int mm = 32 * mg + m * 16 + lr;
        int hadr = (mm >> 1) * 128 + ((((mm & 1) << 6) + (lh << 4)) ^ (((mm >> 1) & 7) << 4));
        ha[m] = *(const bf16x8*)(hsb + hadr);
      }
#pragma unroll
      for (int nt = 0; nt < 8; nt++){
        int n = 128 * ng + nt * 16 + lr;
        int adr = (n >> 1) * 128 + ((((n & 1) << 6) + (lh << 4)) ^ (((n >> 1) & 7) << 4));
        bf16x8 b = *(const bf16x8*)(w2b + adr);
        acc[0][nt] = __builtin_amdgcn_mfma_f32_16x16x32_bf16(ha[0], b, acc[0][nt], 0, 0, 0);
        acc[1][nt] = __builtin_amdgcn_mfma_f32_16x16x32_bf16(ha[1], b, acc[1][nt], 0, 0, 0);
      }
    }
    // ---- end barrier: require chunk c+1 staged, keep chunk c+2 in flight
    if (c + 1 < NCH){
      if (c + 2 < NCH){
        asm volatile("s_waitcnt vmcnt(4) lgkmcnt(0)" ::: "memory");
      } else {
        asm volatile("s_waitcnt vmcnt(0) lgkmcnt(0)" ::: "memory");
      }
      __builtin_amdgcn_sched_barrier(0);
      __builtin_amdgcn_s_barrier();
      __builtin_amdgcn_sched_barrier(0);
    }
  }

  // ---- epilogue: fold gate weight + b2, store token-major bf16 rows
#pragma unroll
  for (int m = 0; m < 2; m++){
    float wrow[4]; int yrow[4]; int valid[4];
#pragma unroll
    for (int r = 0; r < 4; r++){
      int gg = rs + 32 * mg + m * 16 + lh * 4 + r;
      valid[r] = gg < re;
      int gc = valid[r] ? gg : (re - 1);
      int pt = pair_tok[gc];
      yrow[r] = (pt & 0xFFFF) * 2 + (pt >> 16);
      wrow[r] = valid[r] ? pair_w[gc] : 0.f;
    }
#pragma unroll
    for (int nt = 0; nt < 8; nt++){
      int col = 128 * ng + nt * 16 + lr;
      float b2v = b2[e * DOUT + col];
#pragma unroll
      for (int r = 0; r < 4; r++){
        if (valid[r])
          ypair[(size_t)yrow[r] * DOUT + col] = f2bf(wrow[r] * (acc[m][nt][r] + b2v));
      }
    }
  }
#undef STAGE
}

// ---------------- combine: out[t] = yp[2t] + yp[2t+1], fully coalesced
__global__ __launch_bounds__(256) void combine_kernel(const unsigned short* __restrict__ yp,
                                                      float* __restrict__ out){
  int idx = blockIdx.x * 256 + threadIdx.x;
  int t = idx >> 6;
  int c4 = (idx & 63) << 2;
  ushort4 a = *(const ushort4*)(yp + (size_t)(t * 2) * DOUT + c4);
  ushort4 b = *(const ushort4*)(yp + (size_t)(t * 2 + 1) * DOUT + c4);
  float4 o;
  o.x = bf2f(a.x) + bf2f(b.x);
  o.y = bf2f(a.y) + bf2f(b.y);
  o.z = bf2f(a.z) + bf2f(b.z);
  o.w = bf2f(a.w) + bf2f(b.w);
  *(float4*)(out + (size_t)t * DOUT + c4) = o;
}

extern "C" void kernel_launch(void* const* d_in, const int* in_sizes, int n_in,
                              void* d_out, int out_size, void* d_ws, size_t ws_size,
                              hipStream_t stream){
  (void)in_sizes; (void)n_in; (void)out_size; (void)ws_size;
  const float* x  = (const float*)d_in[0];
  const float* Wg = (const float*)d_in[1];
  const float* bg = (const float*)d_in[2];
  const float* W1 = (const float*)d_in[3];
  const float* b1 = (const float*)d_in[4];
  const float* W2 = (const float*)d_in[5];
  const float* b2 = (const float*)d_in[6];
  float* out = (float*)d_out;
  char* ws = (char*)d_ws;

  unsigned short* x_bf  = (unsigned short*)(ws);                 // 16,777,216
  unsigned short* W1t   = (unsigned short*)(ws + 16777216);      //  4,194,304
  unsigned short* W2ck  = (unsigned short*)(ws + 20971520);      //  4,194,304
  unsigned short* ypair = (unsigned short*)(ws + 25165824);      // 33,554,432
  int*   top_idx  = (int*)  (ws + 58720256);
  float* top_w    = (float*)(ws + 58982400);
  int*   pair_tok = (int*)  (ws + 59244544);
  float* pair_w   = (float*)(ws + 59506688);
  int*   counts   = (int*)  (ws + 60030976);
  int*   offsets  = (int*)  (ws + 60031040);
  int*   cursor   = (int*)  (ws + 60031104);
  int*   bm_e     = (int*)  (ws + 60031232);   // 768 ints
  int*   bm_start = (int*)  (ws + 60036608);   // 768 ints
  int*   bm_end   = (int*)  (ws + 60041984);   // 768 ints

  hipMemsetAsync(counts, 0, 64, stream);
  transpose_cvt<<<dim3(16, 8, 16), 256, 0, stream>>>(W1, W1t, 256, 512);
  transpose_cvt_w2<<<dim3(8, 16, 16), 256, 0, stream>>>(W2, W2ck);
  gating_kernel<<<512, 256, 0, stream>>>(x, Wg, bg, x_bf, top_idx, top_w, counts);
  prefix_kernel<<<1, 64, 0, stream>>>(counts, offsets, cursor, bm_e, bm_start, bm_end);
  scatter_kernel<<<128, 256, 0, stream>>>(top_idx, top_w, cursor, pair_tok, pair_w);
  moe_gemm_kernel<<<8 * SLOTS, 512, 0, stream>>>(x_bf, W1t, W2ck, b1, b2, pair_tok, pair_w,
                                                 bm_e, bm_start, bm_end, ypair);
  combine_kernel<<<8192, 256, 0, stream>>>(ypair, out);
}

// Round 14
// 166.879 us; speedup vs baseline: 1.7285x; 1.0436x over previous
//
#include <hip/hip_runtime.h>
#include <stdint.h>

#define BTOK 32768
#define DIN 256
#define DHID 512
#define DOUT 256
#define NEXP 16
#define BM 64
#define CH 32
#define NCH 16
#define SLOTS 168

typedef __attribute__((ext_vector_type(8))) short bf16x8;
typedef __attribute__((ext_vector_type(4))) float f32x4;

__device__ __forceinline__ unsigned short f2bf(float f){
  unsigned u = __builtin_bit_cast(unsigned, f);
  u = u + 0x7FFFu + ((u >> 16) & 1u);      // RNE, finite inputs only
  return (unsigned short)(u >> 16);
}
__device__ __forceinline__ float bf2f(unsigned short h){
  return __builtin_bit_cast(float, (unsigned)h << 16);
}
__device__ __forceinline__ void gload16(const void* g, void* l){
  __builtin_amdgcn_global_load_lds((const __attribute__((address_space(1))) unsigned int*)g,
                                   (__attribute__((address_space(3))) unsigned int*)l, 16, 0, 0);
}

// ---------------- W1 transpose + cvt: src[e][256 i][512 h] -> dst[e][512 h][256 i]
__global__ __launch_bounds__(256) void transpose_cvt(const float* __restrict__ src,
                                                     unsigned short* __restrict__ dst,
                                                     int R, int C){
  __shared__ float t[32][33];
  int e = blockIdx.z, r0 = blockIdx.y * 32, c0 = blockIdx.x * 32;
  int lx = threadIdx.x & 31, ly = threadIdx.x >> 5;
  const float* s = src + (size_t)e * R * C;
  unsigned short* d = dst + (size_t)e * R * C;
#pragma unroll
  for (int i = 0; i < 4; i++){ int r = ly + i * 8; t[r][lx] = s[(size_t)(r0 + r) * C + c0 + lx]; }
  __syncthreads();
#pragma unroll
  for (int i = 0; i < 4; i++){ int r = ly + i * 8; d[(size_t)(c0 + r) * R + r0 + lx] = f2bf(t[lx][r]); }
}

// ---------------- W2 transpose + cvt into chunk-major: src[e][512 h][256 o] -> dst[e][16][256 o][32 h]
__global__ __launch_bounds__(256) void transpose_cvt_w2(const float* __restrict__ src,
                                                        unsigned short* __restrict__ dst){
  __shared__ float t[32][33];
  int e = blockIdx.z, r0 = blockIdx.y * 32, c0 = blockIdx.x * 32;   // r0 over h, c0 over o
  int lx = threadIdx.x & 31, ly = threadIdx.x >> 5;
  const float* s = src + (size_t)e * DHID * DOUT;
  unsigned short* d = dst + (size_t)e * DHID * DOUT + (r0 >> 5) * (DOUT * CH);
#pragma unroll
  for (int i = 0; i < 4; i++){ int r = ly + i * 8; t[r][lx] = s[(size_t)(r0 + r) * DOUT + c0 + lx]; }
  __syncthreads();
#pragma unroll
  for (int i = 0; i < 4; i++){ int rr = ly + i * 8; d[(size_t)(c0 + rr) * CH + lx] = f2bf(t[lx][rr]); }
}

// ---------------- gating: 512 blocks x 64 tokens; LDS-aggregated histogram
__global__ __launch_bounds__(256) void gating_kernel(const float* __restrict__ x,
                                                     const float* __restrict__ Wg,
                                                     const float* __restrict__ bg,
                                                     unsigned short* __restrict__ x_bf,
                                                     int* __restrict__ top_idx,
                                                     float* __restrict__ top_w,
                                                     int* __restrict__ counts){
  __shared__ float WgT[16][256];
  __shared__ int hist[16];
  int tid = threadIdx.x;
#pragma unroll
  for (int j = 0; j < 4; j++){
    float4 wv = *(const float4*)(Wg + tid * 16 + j * 4);
    WgT[j * 4 + 0][tid] = wv.x; WgT[j * 4 + 1][tid] = wv.y;
    WgT[j * 4 + 2][tid] = wv.z; WgT[j * 4 + 3][tid] = wv.w;
  }
  if (tid < 16) hist[tid] = 0;
  __syncthreads();
  int wid = tid >> 6, lane = tid & 63;

  for (int t = 0; t < 16; t++){
    int tok = blockIdx.x * 64 + wid * 16 + t;
    const float4 xv = *(const float4*)(x + (size_t)tok * DIN + lane * 4);
    ushort4 xb; xb.x = f2bf(xv.x); xb.y = f2bf(xv.y); xb.z = f2bf(xv.z); xb.w = f2bf(xv.w);
    *(ushort4*)(x_bf + (size_t)tok * DIN + lane * 4) = xb;
    float logit[16];
#pragma unroll
    for (int e = 0; e < 16; e++){
      const float4 wv = *(const float4*)(&WgT[e][lane * 4]);
      float v = xv.x * wv.x + xv.y * wv.y + xv.z * wv.z + xv.w * wv.w;
#pragma unroll
      for (int off = 32; off; off >>= 1) v += __shfl_xor(v, off, 64);
      logit[e] = v + bg[e];
    }
    if (lane == 0){
      int i1 = 0; float v1 = logit[0];
#pragma unroll
      for (int e = 1; e < 16; e++) if (logit[e] > v1){ v1 = logit[e]; i1 = e; }
      int i2 = -1; float v2 = -3.4e38f;
#pragma unroll
      for (int e = 0; e < 16; e++) if (e != i1 && logit[e] > v2){ v2 = logit[e]; i2 = e; }
      float tt = expf(v2 - v1);
      float w1 = 1.0f / (1.0f + tt);
      float w2 = tt / (1.0f + tt);
      top_idx[tok * 2] = i1; top_idx[tok * 2 + 1] = i2;
      top_w[tok * 2] = w1;  top_w[tok * 2 + 1] = w2;
      atomicAdd(&hist[i1], 1); atomicAdd(&hist[i2], 1);
    }
  }
  __syncthreads();
  if (tid < 16) atomicAdd(&counts[tid], hist[tid]);
}

// ---------------- prefix sum + XCD-affine block map (one wave)
__global__ void prefix_kernel(const int* __restrict__ counts, int* __restrict__ offsets,
                              int* __restrict__ cursor, int* __restrict__ bm_e,
                              int* __restrict__ bm_start, int* __restrict__ bm_end){
  int lane = threadIdx.x & 63;
  int c = (lane < 16) ? counts[lane] : 0;
  int s = c;
#pragma unroll
  for (int off = 1; off < 16; off <<= 1){ int o = __shfl_up(s, off, 64); if (lane >= off) s += o; }
  int start = s - c;
  if (lane < 16){ offsets[lane] = start; cursor[lane] = start; }
  int nb = (c + BM - 1) >> 6;
  int nb_partner = __shfl(nb, lane ^ 8, 64);
  if (lane < 8){
    int filled = nb + nb_partner;
    if (filled > SLOTS) filled = SLOTS;
    for (int i = filled; i < SLOTS; i++) bm_e[lane * SLOTS + i] = -1;
  }
  if (lane < 16){
    int sbase = (lane < 8) ? 0 : nb_partner;
    int xcd = lane & 7;
    for (int b = 0; b < nb; b++){
      int idx = xcd * SLOTS + sbase + b;
      if (sbase + b < SLOTS){
        bm_e[idx] = lane; bm_start[idx] = start + b * BM; bm_end[idx] = start + c;
      }
    }
  }
}

// ---------------- scatter: block-aggregated chunk reservation, LDS ranks
// pair_tok packs token | (k << 16) so the gemm can write token-major ypair.
__global__ __launch_bounds__(256) void scatter_kernel(const int* __restrict__ top_idx,
                                                      const float* __restrict__ top_w,
                                                      int* __restrict__ cursor,
                                                      int* __restrict__ pair_tok,
                                                      float* __restrict__ pair_w){
  __shared__ int hist[16], base[16], rank[16];
  int tid = threadIdx.x;
  if (tid < 16){ hist[tid] = 0; rank[tid] = 0; }
  __syncthreads();
  int t = blockIdx.x * 256 + tid;
  int e0 = top_idx[t * 2], e1 = top_idx[t * 2 + 1];
  float w0 = top_w[t * 2], w1 = top_w[t * 2 + 1];
  atomicAdd(&hist[e0], 1); atomicAdd(&hist[e1], 1);
  __syncthreads();
  if (tid < 16) base[tid] = atomicAdd(&cursor[tid], hist[tid]);
  __syncthreads();
  int r0 = atomicAdd(&rank[e0], 1);
  int p0 = base[e0] + r0;
  pair_tok[p0] = t; pair_w[p0] = w0;
  int r1 = atomicAdd(&rank[e1], 1);
  int p1 = base[e1] + r1;
  pair_tok[p1] = t | (1 << 16); pair_w[p1] = w1;
}

// ---------------- fused 2-layer expert MLP v14: OCCUPANCY build.
// BM=64, 8 waves (4mg x 2ng); wave = M=16 tokens x N=128 -> xr 32 + acc 32
// AGPR + temps ~ 90 regs <= 128 cap -> 4 waves/SIMD; 68KB LDS -> 2 blocks/CU
// = 16 waves/CU. Dbuf W staging (global_load_lds), 2 barriers/chunk; the
// co-resident block covers drains. All R13 swizzles/mappings verbatim.
__global__ __launch_bounds__(512, 4) void moe_gemm_kernel(
    const unsigned short* __restrict__ x_bf,   // [B][256]
    const unsigned short* __restrict__ W1t,    // [E][512 h][256 i]
    const unsigned short* __restrict__ W2c,    // [E][16 c][256 o][32 h]
    const float* __restrict__ b1,              // [E][512]
    const float* __restrict__ b2,              // [E][256]
    const int* __restrict__ pair_tok, const float* __restrict__ pair_w,
    const int* __restrict__ bm_e, const int* __restrict__ bm_start,
    const int* __restrict__ bm_end,
    unsigned short* __restrict__ ypair){       // [B*2][256] bf16, token-major
  int xcd = blockIdx.x & 7, slot = blockIdx.x >> 3;
  int bmi = xcd * SLOTS + slot;
  int e = bm_e[bmi];
  if (e < 0) return;
  int rs = bm_start[bmi], re = bm_end[bmi];

  __shared__ unsigned short w1s[2][CH * 256];   // 2x16KB [h row][i], 512B rows, XOR
  __shared__ unsigned short w2s[2][256 * CH];   // 2x16KB [o row][h], row-pair 128B XOR
  __shared__ unsigned short hs[BM * CH];        // 4KB [m 64][h 32], row-pair XOR

  int tid = threadIdx.x, wid = tid >> 6, lane = tid & 63, lr = lane & 15, lh = lane >> 4;
  int mg = wid >> 1, ng = wid & 1;
  char* hsb = (char*)hs;
  const char* gW1 = (const char*)(W1t + (size_t)e * DHID * DIN);
  const char* gW2 = (const char*)(W2c + (size_t)e * DOUT * DHID);

  // per-lane staging source offsets (pre-swizzled; +8192 keeps XOR row bits)
  int o1 = ((tid >> 5) * 512) + (((tid & 31) ^ ((tid >> 5) & 7)) * 16);
  int o2;
  { int p = tid >> 3, q = (tid & 7) ^ (p & 7);
    o2 = (p * 2 + (q >> 2)) * 64 + (q & 3) * 16; }

#define STAGE(c, sl) {                                                    \
    const char* s1 = gW1 + (size_t)(c) * 16384;                           \
    const char* s2 = gW2 + (size_t)(c) * 16384;                           \
    char* d1 = (char*)w1s[sl]; char* d2 = (char*)w2s[sl];                 \
    gload16(s1 + o1,        d1 + tid * 16);                               \
    gload16(s1 + o1 + 8192, d1 + tid * 16 + 8192);                        \
    gload16(s2 + o2,        d2 + tid * 16);                               \
    gload16(s2 + o2 + 8192, d2 + tid * 16 + 8192);                        \
  }

  // ---- x rows (wave's 16 tokens) -> registers (32 VGPR)
  bf16x8 xr[8];
  {
    int g0 = rs + 16 * mg + lr;
    int gc = g0 < re ? g0 : (re - 1);
    int tok = pair_tok[gc] & 0xFFFF;
    const unsigned short* xrow = x_bf + (size_t)tok * DIN + lh * 8;
#pragma unroll
    for (int ks = 0; ks < 8; ks++) xr[ks] = *(const bf16x8*)(xrow + ks * 32);
  }

  f32x4 acc[8];
#pragma unroll
  for (int i = 0; i < 8; i++) acc[i] = (f32x4){0.f, 0.f, 0.f, 0.f};

  STAGE(0, 0);
  __syncthreads();                       // chunk-0 staged

  for (int c = 0; c < NCH; c++){
    int sl = c & 1;
    if (c + 1 < NCH) STAGE(c + 1, sl ^ 1);   // in flight under this chunk

    // ---- phase A: wave computes h[16 tok of mg][16 hid of ng]
    {
      const char* w1b = (const char*)w1s[sl];
      f32x4 hacc = (f32x4){0.f, 0.f, 0.f, 0.f};
      int hrow = 16 * ng + lr;
#pragma unroll
      for (int ks = 0; ks < 8; ks++){
        bf16x8 b = *(const bf16x8*)(w1b + ((hrow * 512 + ks * 64 + lh * 16) ^ ((hrow & 7) << 4)));
        hacc = __builtin_amdgcn_mfma_f32_16x16x32_bf16(xr[ks], b, hacc, 0, 0, 0);
      }
      float b1v = b1[e * DHID + c * CH + 16 * ng + lr];
      int col2 = (16 * ng + lr) * 2;
#pragma unroll
      for (int r = 0; r < 4; r++){
        int mm = 16 * mg + lh * 4 + r;
        float v = fmaxf(hacc[r] + b1v, 0.f);
        int adr = (mm >> 1) * 128 + ((((mm & 1) << 6) + col2) ^ (((mm >> 1) & 7) << 4));
        *(unsigned short*)(hsb + adr) = f2bf(v);
      }
    }
    __syncthreads();                     // hs published (both ng halves)

    // ---- phase B: y[16 tok of mg][128 cols of ng] += h @ W2c
    {
      int mm = 16 * mg + lr;
      int hadr = (mm >> 1) * 128 + ((((mm & 1) << 6) + (lh << 4)) ^ (((mm >> 1) & 7) << 4));
      bf16x8 ha = *(const bf16x8*)(hsb + hadr);
      const char* w2b = (const char*)w2s[sl];
#pragma unroll
      for (int nt = 0; nt < 8; nt++){
        int n = 128 * ng + nt * 16 + lr;
        int adr = (n >> 1) * 128 + ((((n & 1) << 6) + (lh << 4)) ^ (((n >> 1) & 7) << 4));
        bf16x8 b = *(const bf16x8*)(w2b + adr);
        acc[nt] = __builtin_amdgcn_mfma_f32_16x16x32_bf16(ha, b, acc[nt], 0, 0, 0);
      }
    }
    __syncthreads();                     // next chunk staged; hs free
  }

  // ---- epilogue: fold gate weight + b2, store token-major bf16 rows
  {
    float wrow[4]; int yrow[4]; int valid[4];
#pragma unroll
    for (int r = 0; r < 4; r++){
      int gg = rs + 16 * mg + lh * 4 + r;
      valid[r] = gg < re;
      int gc = valid[r] ? gg : (re - 1);
      int pt = pair_tok[gc];
      yrow[r] = (pt & 0xFFFF) * 2 + (pt >> 16);
      wrow[r] = valid[r] ? pair_w[gc] : 0.f;
    }
#pragma unroll
    for (int nt = 0; nt < 8; nt++){
      int col = 128 * ng + nt * 16 + lr;
      float b2v = b2[e * DOUT + col];
#pragma unroll
      for (int r = 0; r < 4; r++){
        if (valid[r])
          ypair[(size_t)yrow[r] * DOUT + col] = f2bf(wrow[r] * (acc[nt][r] + b2v));
      }
    }
  }
#undef STAGE
}

// ---------------- combine: out[t] = yp[2t] + yp[2t+1], fully coalesced
__global__ __launch_bounds__(256) void combine_kernel(const unsigned short* __restrict__ yp,
                                                      float* __restrict__ out){
  int idx = blockIdx.x * 256 + threadIdx.x;
  int t = idx >> 6;
  int c4 = (idx & 63) << 2;
  ushort4 a = *(const ushort4*)(yp + (size_t)(t * 2) * DOUT + c4);
  ushort4 b = *(const ushort4*)(yp + (size_t)(t * 2 + 1) * DOUT + c4);
  float4 o;
  o.x = bf2f(a.x) + bf2f(b.x);
  o.y = bf2f(a.y) + bf2f(b.y);
  o.z = bf2f(a.z) + bf2f(b.z);
  o.w = bf2f(a.w) + bf2f(b.w);
  *(float4*)(out + (size_t)t * DOUT + c4) = o;
}

extern "C" void kernel_launch(void* const* d_in, const int* in_sizes, int n_in,
                              void* d_out, int out_size, void* d_ws, size_t ws_size,
                              hipStream_t stream){
  (void)in_sizes; (void)n_in; (void)out_size; (void)ws_size;
  const float* x  = (const float*)d_in[0];
  const float* Wg = (const float*)d_in[1];
  const float* bg = (const float*)d_in[2];
  const float* W1 = (const float*)d_in[3];
  const float* b1 = (const float*)d_in[4];
  const float* W2 = (const float*)d_in[5];
  const float* b2 = (const float*)d_in[6];
  float* out = (float*)d_out;
  char* ws = (char*)d_ws;

  unsigned short* x_bf  = (unsigned short*)(ws);                 // 16,777,216
  unsigned short* W1t   = (unsigned short*)(ws + 16777216);      //  4,194,304
  unsigned short* W2ck  = (unsigned short*)(ws + 20971520);      //  4,194,304
  unsigned short* ypair = (unsigned short*)(ws + 25165824);      // 33,554,432
  int*   top_idx  = (int*)  (ws + 58720256);
  float* top_w    = (float*)(ws + 58982400);
  int*   pair_tok = (int*)  (ws + 59244544);
  float* pair_w   = (float*)(ws + 59506688);
  int*   counts   = (int*)  (ws + 60030976);
  int*   offsets  = (int*)  (ws + 60031040);
  int*   cursor   = (int*)  (ws + 60031104);
  int*   bm_e     = (int*)  (ws + 60031232);   // 1344 ints
  int*   bm_start = (int*)  (ws + 60036608);   // 1344 ints
  int*   bm_end   = (int*)  (ws + 60041984);   // 1344 ints

  hipMemsetAsync(counts, 0, 64, stream);
  transpose_cvt<<<dim3(16, 8, 16), 256, 0, stream>>>(W1, W1t, 256, 512);
  transpose_cvt_w2<<<dim3(8, 16, 16), 256, 0, stream>>>(W2, W2ck);
  gating_kernel<<<512, 256, 0, stream>>>(x, Wg, bg, x_bf, top_idx, top_w, counts);
  prefix_kernel<<<1, 64, 0, stream>>>(counts, offsets, cursor, bm_e, bm_start, bm_end);
  scatter_kernel<<<128, 256, 0, stream>>>(top_idx, top_w, cursor, pair_tok, pair_w);
  moe_gemm_kernel<<<8 * SLOTS, 512, 0, stream>>>(x_bf, W1t, W2ck, b1, b2, pair_tok, pair_w,
                                                 bm_e, bm_start, bm_end, ypair);
  combine_kernel<<<8192, 256, 0, stream>>>(ypair, out);
}

// Round 15
// 159.517 us; speedup vs baseline: 1.8083x; 1.0462x over previous
//
#include <hip/hip_runtime.h>
#include <stdint.h>

#define BTOK 32768
#define DIN 256
#define DHID 512
#define DOUT 256
#define NEXP 16
#define BM 128
#define CH 64
#define NCH 8
#define SLOTS 96

typedef __attribute__((ext_vector_type(8))) short bf16x8;
typedef __attribute__((ext_vector_type(16))) float f32x16;

__device__ __forceinline__ unsigned short f2bf(float f){
  unsigned u = __builtin_bit_cast(unsigned, f);
  u = u + 0x7FFFu + ((u >> 16) & 1u);      // RNE, finite inputs only
  return (unsigned short)(u >> 16);
}
__device__ __forceinline__ float bf2f(unsigned short h){
  return __builtin_bit_cast(float, (unsigned)h << 16);
}
__device__ __forceinline__ void gload16(const void* g, void* l){
  __builtin_amdgcn_global_load_lds((const __attribute__((address_space(1))) unsigned int*)g,
                                   (__attribute__((address_space(3))) unsigned int*)l, 16, 0, 0);
}

// ---------------- W1 transpose + cvt: src[e][256 i][512 h] -> dst[e][512 h][256 i]
__global__ __launch_bounds__(256) void transpose_cvt(const float* __restrict__ src,
                                                     unsigned short* __restrict__ dst,
                                                     int R, int C){
  __shared__ float t[32][33];
  int e = blockIdx.z, r0 = blockIdx.y * 32, c0 = blockIdx.x * 32;
  int lx = threadIdx.x & 31, ly = threadIdx.x >> 5;
  const float* s = src + (size_t)e * R * C;
  unsigned short* d = dst + (size_t)e * R * C;
#pragma unroll
  for (int i = 0; i < 4; i++){ int r = ly + i * 8; t[r][lx] = s[(size_t)(r0 + r) * C + c0 + lx]; }
  __syncthreads();
#pragma unroll
  for (int i = 0; i < 4; i++){ int r = ly + i * 8; d[(size_t)(c0 + r) * R + r0 + lx] = f2bf(t[lx][r]); }
}

// ---------------- W2 transpose + cvt into chunk-major: src[e][512 h][256 o] -> dst[e][8][256 o][64 h]
__global__ __launch_bounds__(256) void transpose_cvt_w2(const float* __restrict__ src,
                                                        unsigned short* __restrict__ dst){
  __shared__ float t[32][33];
  int e = blockIdx.z, r0 = blockIdx.y * 32, c0 = blockIdx.x * 32;   // r0 over h, c0 over o
  int lx = threadIdx.x & 31, ly = threadIdx.x >> 5;
  const float* s = src + (size_t)e * DHID * DOUT;
  unsigned short* d = dst + (size_t)e * DHID * DOUT + (r0 >> 6) * (DOUT * CH) + (r0 & 32);
#pragma unroll
  for (int i = 0; i < 4; i++){ int r = ly + i * 8; t[r][lx] = s[(size_t)(r0 + r) * DOUT + c0 + lx]; }
  __syncthreads();
#pragma unroll
  for (int i = 0; i < 4; i++){ int rr = ly + i * 8; d[(size_t)(c0 + rr) * CH + lx] = f2bf(t[lx][rr]); }
}

// ---------------- gating: 512 blocks x 64 tokens; LDS-aggregated histogram
__global__ __launch_bounds__(256) void gating_kernel(const float* __restrict__ x,
                                                     const float* __restrict__ Wg,
                                                     const float* __restrict__ bg,
                                                     unsigned short* __restrict__ x_bf,
                                                     int* __restrict__ top_idx,
                                                     float* __restrict__ top_w,
                                                     int* __restrict__ counts){
  __shared__ float WgT[16][256];
  __shared__ int hist[16];
  int tid = threadIdx.x;
#pragma unroll
  for (int j = 0; j < 4; j++){
    float4 wv = *(const float4*)(Wg + tid * 16 + j * 4);
    WgT[j * 4 + 0][tid] = wv.x; WgT[j * 4 + 1][tid] = wv.y;
    WgT[j * 4 + 2][tid] = wv.z; WgT[j * 4 + 3][tid] = wv.w;
  }
  if (tid < 16) hist[tid] = 0;
  __syncthreads();
  int wid = tid >> 6, lane = tid & 63;

  for (int t = 0; t < 16; t++){
    int tok = blockIdx.x * 64 + wid * 16 + t;
    const float4 xv = *(const float4*)(x + (size_t)tok * DIN + lane * 4);
    ushort4 xb; xb.x = f2bf(xv.x); xb.y = f2bf(xv.y); xb.z = f2bf(xv.z); xb.w = f2bf(xv.w);
    *(ushort4*)(x_bf + (size_t)tok * DIN + lane * 4) = xb;
    float logit[16];
#pragma unroll
    for (int e = 0; e < 16; e++){
      const float4 wv = *(const float4*)(&WgT[e][lane * 4]);
      float v = xv.x * wv.x + xv.y * wv.y + xv.z * wv.z + xv.w * wv.w;
#pragma unroll
      for (int off = 32; off; off >>= 1) v += __shfl_xor(v, off, 64);
      logit[e] = v + bg[e];
    }
    if (lane == 0){
      int i1 = 0; float v1 = logit[0];
#pragma unroll
      for (int e = 1; e < 16; e++) if (logit[e] > v1){ v1 = logit[e]; i1 = e; }
      int i2 = -1; float v2 = -3.4e38f;
#pragma unroll
      for (int e = 0; e < 16; e++) if (e != i1 && logit[e] > v2){ v2 = logit[e]; i2 = e; }
      float tt = expf(v2 - v1);
      float w1 = 1.0f / (1.0f + tt);
      float w2 = tt / (1.0f + tt);
      top_idx[tok * 2] = i1; top_idx[tok * 2 + 1] = i2;
      top_w[tok * 2] = w1;  top_w[tok * 2 + 1] = w2;
      atomicAdd(&hist[i1], 1); atomicAdd(&hist[i2], 1);
    }
  }
  __syncthreads();
  if (tid < 16) atomicAdd(&counts[tid], hist[tid]);
}

// ---------------- prefix sum + XCD-affine block map (one wave)
__global__ void prefix_kernel(const int* __restrict__ counts, int* __restrict__ offsets,
                              int* __restrict__ cursor, int* __restrict__ bm_e,
                              int* __restrict__ bm_start, int* __restrict__ bm_end){
  int lane = threadIdx.x & 63;
  int c = (lane < 16) ? counts[lane] : 0;
  int s = c;
#pragma unroll
  for (int off = 1; off < 16; off <<= 1){ int o = __shfl_up(s, off, 64); if (lane >= off) s += o; }
  int start = s - c;
  if (lane < 16){ offsets[lane] = start; cursor[lane] = start; }
  int nb = (c + BM - 1) >> 7;
  int nb_partner = __shfl(nb, lane ^ 8, 64);
  if (lane < 8){
    int filled = nb + nb_partner;
    if (filled > SLOTS) filled = SLOTS;
    for (int i = filled; i < SLOTS; i++) bm_e[lane * SLOTS + i] = -1;
  }
  if (lane < 16){
    int sbase = (lane < 8) ? 0 : nb_partner;
    int xcd = lane & 7;
    for (int b = 0; b < nb; b++){
      int idx = xcd * SLOTS + sbase + b;
      if (sbase + b < SLOTS){
        bm_e[idx] = lane; bm_start[idx] = start + b * BM; bm_end[idx] = start + c;
      }
    }
  }
}

// ---------------- scatter: block-aggregated chunk reservation, LDS ranks
// pair_tok packs token | (k << 16) so the gemm can write token-major ypair.
__global__ __launch_bounds__(256) void scatter_kernel(const int* __restrict__ top_idx,
                                                      const float* __restrict__ top_w,
                                                      int* __restrict__ cursor,
                                                      int* __restrict__ pair_tok,
                                                      float* __restrict__ pair_w){
  __shared__ int hist[16], base[16], rank[16];
  int tid = threadIdx.x;
  if (tid < 16){ hist[tid] = 0; rank[tid] = 0; }
  __syncthreads();
  int t = blockIdx.x * 256 + tid;
  int e0 = top_idx[t * 2], e1 = top_idx[t * 2 + 1];
  float w0 = top_w[t * 2], w1 = top_w[t * 2 + 1];
  atomicAdd(&hist[e0], 1); atomicAdd(&hist[e1], 1);
  __syncthreads();
  if (tid < 16) base[tid] = atomicAdd(&cursor[tid], hist[tid]);
  __syncthreads();
  int r0 = atomicAdd(&rank[e0], 1);
  int p0 = base[e0] + r0;
  pair_tok[p0] = t; pair_w[p0] = w0;
  int r1 = atomicAdd(&rank[e1], 1);
  int p1 = base[e1] + r1;
  pair_tok[p1] = t | (1 << 16); pair_w[p1] = w1;
}

// ---------------- fused 2-layer expert MLP v15: 32x32x16 MFMA (2x FLOP per LDS
// read and per register vs 16x16x32). BM=128, 8 waves (4mg x 2hg), CH=64.
// Phase A: wave owns one 32x32 h-tile (K=256, 16 MFMA, 2 dep-chains).
// Phase B: wave = M=32 x N=128 (4 out-tiles, K=64). All LDS layouts use
// 16-granule XOR swizzles -> 2-way (free) bank access. Dbuf W staging via
// global_load_lds issued a full chunk ahead; 2 raw barriers/chunk.
__global__ __launch_bounds__(512, 1) void moe_gemm_kernel(
    const unsigned short* __restrict__ x_bf,   // [B][256]
    const unsigned short* __restrict__ W1t,    // [E][512 h][256 i]
    const unsigned short* __restrict__ W2c,    // [E][8 c][256 o][64 h]
    const float* __restrict__ b1,              // [E][512]
    const float* __restrict__ b2,              // [E][256]
    const int* __restrict__ pair_tok, const float* __restrict__ pair_w,
    const int* __restrict__ bm_e, const int* __restrict__ bm_start,
    const int* __restrict__ bm_end,
    unsigned short* __restrict__ ypair){       // [B*2][256] bf16, token-major
  int xcd = blockIdx.x & 7, slot = blockIdx.x >> 3;
  int bmi = xcd * SLOTS + slot;
  int e = bm_e[bmi];
  if (e < 0) return;
  int rs = bm_start[bmi], re = bm_end[bmi];

  __shared__ unsigned short w1s[2][CH * 256];   // 2x32KB [64 hid][256 k], 512B rows, ^(hid&15)<<4
  __shared__ unsigned short w2s[2][256 * CH];   // 2x32KB [256 o][64 k], 256B row-pairs, ^(pair&15)<<4
  __shared__ unsigned short hs[BM * CH];        // 16KB [128 tok][64 h], 256B row-pairs, ^(pair&15)<<4

  int tid = threadIdx.x, wid = tid >> 6, lane = tid & 63;
  int l31 = lane & 31, l5 = lane >> 5;
  int mg = wid >> 1, hg = wid & 1;
  char* hsb = (char*)hs;
  const char* gW1 = (const char*)(W1t + (size_t)e * DHID * DIN);
  const char* gW2 = (const char*)(W2c + (size_t)e * DOUT * DHID);

  // pre-swizzled staging source offsets (linear LDS dest; +k*8192 preserves XOR bits)
  int o1, o2;
  { int r = tid >> 5; o1 = r * 512 + (((tid & 31) ^ (r & 15)) * 16); }
  { int p = tid >> 4; int q = (tid & 15) ^ (p & 15);
    o2 = (p * 2 + (q >> 3)) * 128 + (q & 7) * 16; }

#define STAGE(c, sl) {                                                    \
    const char* s1 = gW1 + (size_t)(c) * 32768;                           \
    const char* s2 = gW2 + (size_t)(c) * 32768;                           \
    char* d1 = (char*)w1s[sl]; char* d2 = (char*)w2s[sl];                 \
    _Pragma("unroll")                                                     \
    for (int k = 0; k < 4; k++){                                          \
      gload16(s1 + o1 + k * 8192, d1 + tid * 16 + k * 8192);              \
      gload16(s2 + o2 + k * 8192, d2 + tid * 16 + k * 8192);              \
    } }

  // ---- x rows (wave's 32 tokens) -> registers: 16 k-frags of 8 bf16 (64 VGPR)
  bf16x8 xr[16];
  {
    int g0 = rs + mg * 32 + l31;
    int gc = g0 < re ? g0 : (re - 1);
    int tok = pair_tok[gc] & 0xFFFF;
    const unsigned short* xrow = x_bf + (size_t)tok * DIN + l5 * 8;
#pragma unroll
    for (int ks = 0; ks < 16; ks++) xr[ks] = *(const bf16x8*)(xrow + ks * 16);
  }

  const f32x16 fzero = {0.f,0.f,0.f,0.f,0.f,0.f,0.f,0.f,0.f,0.f,0.f,0.f,0.f,0.f,0.f,0.f};
  f32x16 acc[4];
  acc[0] = fzero; acc[1] = fzero; acc[2] = fzero; acc[3] = fzero;

  STAGE(0, 0);
  asm volatile("s_waitcnt vmcnt(0)" ::: "memory");
  __builtin_amdgcn_sched_barrier(0);
  __builtin_amdgcn_s_barrier();
  __builtin_amdgcn_sched_barrier(0);

  int hid = hg * 32 + l31;                 // chunk-local hid row this wave reads/writes
  int swzA = (hid & 15) << 4;

  for (int c = 0; c < NCH; c++){
    int sl = c & 1;
    if (c + 1 < NCH) STAGE(c + 1, sl ^ 1);     // lands during this chunk

    float b1v = b1[e * DHID + c * CH + hid];

    // ---- phase A: h-tile[32 tok of mg][32 hid of hg], K=256, 2 dep-chains
    {
      const char* w1b = (const char*)w1s[sl];
      f32x16 h0 = fzero, h1 = fzero;
#pragma unroll
      for (int ks = 0; ks < 16; ks += 2){
        bf16x8 bA = *(const bf16x8*)(w1b + hid * 512 + ((ks * 32 + l5 * 16) ^ swzA));
        bf16x8 bB = *(const bf16x8*)(w1b + hid * 512 + (((ks + 1) * 32 + l5 * 16) ^ swzA));
        h0 = __builtin_amdgcn_mfma_f32_32x32x16_bf16(xr[ks], bA, h0, 0, 0, 0);
        h1 = __builtin_amdgcn_mfma_f32_32x32x16_bf16(xr[ks + 1], bB, h1, 0, 0, 0);
      }
      f32x16 hsum = h0 + h1;
      // relu(h+b1) -> hs (row-pair 256B XOR layout); C/D: col=lane&31,
      // row=(reg&3)+8*(reg>>2)+4*(lane>>5)
      int h2 = hg * 64 + l31 * 2;
#pragma unroll
      for (int r = 0; r < 16; r++){
        int tk = mg * 32 + (r & 3) + ((r >> 2) << 3) + (l5 << 2);
        float v = fmaxf(hsum[r] + b1v, 0.f);
        int adr = (tk >> 1) * 256 + ((((tk & 1) << 7) + h2) ^ (((tk >> 1) & 15) << 4));
        *(unsigned short*)(hsb + adr) = f2bf(v);
      }
    }
    asm volatile("s_waitcnt lgkmcnt(0)" ::: "memory");
    __builtin_amdgcn_sched_barrier(0);
    __builtin_amdgcn_s_barrier();
    __builtin_amdgcn_sched_barrier(0);

    // ---- phase B: y[32 tok of mg][128 out of hg] += h @ W2c (K=64)
    {
      const char* w2b = (const char*)w2s[sl];
      int tk = mg * 32 + l31;
      int hswz = ((tk >> 1) & 15) << 4;
      int hbase = (tk >> 1) * 256;
      int hhi = (tk & 1) << 7;
#pragma unroll
      for (int ks = 0; ks < 4; ks++){
        bf16x8 ha = *(const bf16x8*)(hsb + hbase + ((hhi + ks * 32 + l5 * 16) ^ hswz));
#pragma unroll
        for (int ot = 0; ot < 4; ot++){
          int n = hg * 128 + ot * 32 + l31;
          int adr = (n >> 1) * 256 + ((((n & 1) << 7) + ks * 32 + l5 * 16) ^ (((n >> 1) & 15) << 4));
          bf16x8 bb = *(const bf16x8*)(w2b + adr);
          acc[ot] = __builtin_amdgcn_mfma_f32_32x32x16_bf16(ha, bb, acc[ot], 0, 0, 0);
        }
      }
    }
    if (c + 1 < NCH){
      // stage(c+1) was issued a full chunk ago -> vmcnt(0) is effectively free
      asm volatile("s_waitcnt vmcnt(0) lgkmcnt(0)" ::: "memory");
      __builtin_amdgcn_sched_barrier(0);
      __builtin_amdgcn_s_barrier();
      __builtin_amdgcn_sched_barrier(0);
    }
  }

  // ---- epilogue: fold gate weight + b2, store token-major bf16 rows
  {
    float b2v[4];
#pragma unroll
    for (int ot = 0; ot < 4; ot++) b2v[ot] = b2[e * DOUT + hg * 128 + ot * 32 + l31];
#pragma unroll
    for (int r = 0; r < 16; r++){
      int tl = mg * 32 + (r & 3) + ((r >> 2) << 3) + (l5 << 2);
      int gg = rs + tl;
      if (gg < re){
        int pt = pair_tok[gg];
        int yrow = (pt & 0xFFFF) * 2 + (pt >> 16);
        float w = pair_w[gg];
        unsigned short* yp = ypair + (size_t)yrow * DOUT + hg * 128 + l31;
#pragma unroll
        for (int ot = 0; ot < 4; ot++)
          yp[ot * 32] = f2bf(w * (acc[ot][r] + b2v[ot]));
      }
    }
  }
#undef STAGE
}

// ---------------- combine: out[t] = yp[2t] + yp[2t+1], fully coalesced
__global__ __launch_bounds__(256) void combine_kernel(const unsigned short* __restrict__ yp,
                                                      float* __restrict__ out){
  int idx = blockIdx.x * 256 + threadIdx.x;
  int t = idx >> 6;
  int c4 = (idx & 63) << 2;
  ushort4 a = *(const ushort4*)(yp + (size_t)(t * 2) * DOUT + c4);
  ushort4 b = *(const ushort4*)(yp + (size_t)(t * 2 + 1) * DOUT + c4);
  float4 o;
  o.x = bf2f(a.x) + bf2f(b.x);
  o.y = bf2f(a.y) + bf2f(b.y);
  o.z = bf2f(a.z) + bf2f(b.z);
  o.w = bf2f(a.w) + bf2f(b.w);
  *(float4*)(out + (size_t)t * DOUT + c4) = o;
}

extern "C" void kernel_launch(void* const* d_in, const int* in_sizes, int n_in,
                              void* d_out, int out_size, void* d_ws, size_t ws_size,
                              hipStream_t stream){
  (void)in_sizes; (void)n_in; (void)out_size; (void)ws_size;
  const float* x  = (const float*)d_in[0];
  const float* Wg = (const float*)d_in[1];
  const float* bg = (const float*)d_in[2];
  const float* W1 = (const float*)d_in[3];
  const float* b1 = (const float*)d_in[4];
  const float* W2 = (const float*)d_in[5];
  const float* b2 = (const float*)d_in[6];
  float* out = (float*)d_out;
  char* ws = (char*)d_ws;

  unsigned short* x_bf  = (unsigned short*)(ws);                 // 16,777,216
  unsigned short* W1t   = (unsigned short*)(ws + 16777216);      //  4,194,304
  unsigned short* W2ck  = (unsigned short*)(ws + 20971520);      //  4,194,304
  unsigned short* ypair = (unsigned short*)(ws + 25165824);      // 33,554,432
  int*   top_idx  = (int*)  (ws + 58720256);
  float* top_w    = (float*)(ws + 58982400);
  int*   pair_tok = (int*)  (ws + 59244544);
  float* pair_w   = (float*)(ws + 59506688);
  int*   counts   = (int*)  (ws + 60030976);
  int*   offsets  = (int*)  (ws + 60031040);
  int*   cursor   = (int*)  (ws + 60031104);
  int*   bm_e     = (int*)  (ws + 60031232);   // 768 ints
  int*   bm_start = (int*)  (ws + 60036608);   // 768 ints
  int*   bm_end   = (int*)  (ws + 60041984);   // 768 ints

  hipMemsetAsync(counts, 0, 64, stream);
  transpose_cvt<<<dim3(16, 8, 16), 256, 0, stream>>>(W1, W1t, 256, 512);
  transpose_cvt_w2<<<dim3(8, 16, 16), 256, 0, stream>>>(W2, W2ck);
  gating_kernel<<<512, 256, 0, stream>>>(x, Wg, bg, x_bf, top_idx, top_w, counts);
  prefix_kernel<<<1, 64, 0, stream>>>(counts, offsets, cursor, bm_e, bm_start, bm_end);
  scatter_kernel<<<128, 256, 0, stream>>>(top_idx, top_w, cursor, pair_tok, pair_w);
  moe_gemm_kernel<<<8 * SLOTS, 512, 0, stream>>>(x_bf, W1t, W2ck, b1, b2, pair_tok, pair_w,
                                                 bm_e, bm_start, bm_end, ypair);
  combine_kernel<<<8192, 256, 0, stream>>>(ypair, out);
}

// Round 16
// 158.526 us; speedup vs baseline: 1.8196x; 1.0063x over previous
//
#include <hip/hip_runtime.h>
#include <stdint.h>

#define BTOK 32768
#define DIN 256
#define DHID 512
#define DOUT 256
#define NEXP 16
#define BM 128
#define CH 64
#define NCH 8
#define SLOTS 96

typedef __attribute__((ext_vector_type(8))) short bf16x8;
typedef __attribute__((ext_vector_type(16))) float f32x16;

__device__ __forceinline__ unsigned short f2bf(float f){
  unsigned u = __builtin_bit_cast(unsigned, f);
  u = u + 0x7FFFu + ((u >> 16) & 1u);      // RNE, finite inputs only
  return (unsigned short)(u >> 16);
}
__device__ __forceinline__ float bf2f(unsigned short h){
  return __builtin_bit_cast(float, (unsigned)h << 16);
}
__device__ __forceinline__ void gload16(const void* g, void* l){
  __builtin_amdgcn_global_load_lds((const __attribute__((address_space(1))) unsigned int*)g,
                                   (__attribute__((address_space(3))) unsigned int*)l, 16, 0, 0);
}

// ---------------- W1 transpose + cvt: src[e][256 i][512 h] -> dst[e][512 h][256 i]
__global__ __launch_bounds__(256) void transpose_cvt(const float* __restrict__ src,
                                                     unsigned short* __restrict__ dst,
                                                     int R, int C){
  __shared__ float t[32][33];
  int e = blockIdx.z, r0 = blockIdx.y * 32, c0 = blockIdx.x * 32;
  int lx = threadIdx.x & 31, ly = threadIdx.x >> 5;
  const float* s = src + (size_t)e * R * C;
  unsigned short* d = dst + (size_t)e * R * C;
#pragma unroll
  for (int i = 0; i < 4; i++){ int r = ly + i * 8; t[r][lx] = s[(size_t)(r0 + r) * C + c0 + lx]; }
  __syncthreads();
#pragma unroll
  for (int i = 0; i < 4; i++){ int r = ly + i * 8; d[(size_t)(c0 + r) * R + r0 + lx] = f2bf(t[lx][r]); }
}

// ---------------- W2 transpose + cvt into chunk-major: src[e][512 h][256 o] -> dst[e][8][256 o][64 h]
__global__ __launch_bounds__(256) void transpose_cvt_w2(const float* __restrict__ src,
                                                        unsigned short* __restrict__ dst){
  __shared__ float t[32][33];
  int e = blockIdx.z, r0 = blockIdx.y * 32, c0 = blockIdx.x * 32;   // r0 over h, c0 over o
  int lx = threadIdx.x & 31, ly = threadIdx.x >> 5;
  const float* s = src + (size_t)e * DHID * DOUT;
  unsigned short* d = dst + (size_t)e * DHID * DOUT + (r0 >> 6) * (DOUT * CH) + (r0 & 32);
#pragma unroll
  for (int i = 0; i < 4; i++){ int r = ly + i * 8; t[r][lx] = s[(size_t)(r0 + r) * DOUT + c0 + lx]; }
  __syncthreads();
#pragma unroll
  for (int i = 0; i < 4; i++){ int rr = ly + i * 8; d[(size_t)(c0 + rr) * CH + lx] = f2bf(t[lx][rr]); }
}

// ---------------- gating: 512 blocks x 64 tokens; LDS-aggregated histogram
__global__ __launch_bounds__(256) void gating_kernel(const float* __restrict__ x,
                                                     const float* __restrict__ Wg,
                                                     const float* __restrict__ bg,
                                                     unsigned short* __restrict__ x_bf,
                                                     int* __restrict__ top_idx,
                                                     float* __restrict__ top_w,
                                                     int* __restrict__ counts){
  __shared__ float WgT[16][256];
  __shared__ int hist[16];
  int tid = threadIdx.x;
#pragma unroll
  for (int j = 0; j < 4; j++){
    float4 wv = *(const float4*)(Wg + tid * 16 + j * 4);
    WgT[j * 4 + 0][tid] = wv.x; WgT[j * 4 + 1][tid] = wv.y;
    WgT[j * 4 + 2][tid] = wv.z; WgT[j * 4 + 3][tid] = wv.w;
  }
  if (tid < 16) hist[tid] = 0;
  __syncthreads();
  int wid = tid >> 6, lane = tid & 63;

  for (int t = 0; t < 16; t++){
    int tok = blockIdx.x * 64 + wid * 16 + t;
    const float4 xv = *(const float4*)(x + (size_t)tok * DIN + lane * 4);
    ushort4 xb; xb.x = f2bf(xv.x); xb.y = f2bf(xv.y); xb.z = f2bf(xv.z); xb.w = f2bf(xv.w);
    *(ushort4*)(x_bf + (size_t)tok * DIN + lane * 4) = xb;
    float logit[16];
#pragma unroll
    for (int e = 0; e < 16; e++){
      const float4 wv = *(const float4*)(&WgT[e][lane * 4]);
      float v = xv.x * wv.x + xv.y * wv.y + xv.z * wv.z + xv.w * wv.w;
#pragma unroll
      for (int off = 32; off; off >>= 1) v += __shfl_xor(v, off, 64);
      logit[e] = v + bg[e];
    }
    if (lane == 0){
      int i1 = 0; float v1 = logit[0];
#pragma unroll
      for (int e = 1; e < 16; e++) if (logit[e] > v1){ v1 = logit[e]; i1 = e; }
      int i2 = -1; float v2 = -3.4e38f;
#pragma unroll
      for (int e = 0; e < 16; e++) if (e != i1 && logit[e] > v2){ v2 = logit[e]; i2 = e; }
      float tt = expf(v2 - v1);
      float w1 = 1.0f / (1.0f + tt);
      float w2 = tt / (1.0f + tt);
      top_idx[tok * 2] = i1; top_idx[tok * 2 + 1] = i2;
      top_w[tok * 2] = w1;  top_w[tok * 2 + 1] = w2;
      atomicAdd(&hist[i1], 1); atomicAdd(&hist[i2], 1);
    }
  }
  __syncthreads();
  if (tid < 16) atomicAdd(&counts[tid], hist[tid]);
}

// ---------------- prefix sum + XCD unit lists + steal cursors (one wave)
__global__ void prefix_kernel(const int* __restrict__ counts, int* __restrict__ offsets,
                              int* __restrict__ cursor, int* __restrict__ bm_e,
                              int* __restrict__ bm_start, int* __restrict__ bm_end,
                              int* __restrict__ xcd_cnt, int* __restrict__ xcd_cur){
  int lane = threadIdx.x & 63;
  int c = (lane < 16) ? counts[lane] : 0;
  int s = c;
#pragma unroll
  for (int off = 1; off < 16; off <<= 1){ int o = __shfl_up(s, off, 64); if (lane >= off) s += o; }
  int start = s - c;
  if (lane < 16){ offsets[lane] = start; cursor[lane] = start; }
  int nb = (c + BM - 1) >> 7;
  int nb_partner = __shfl(nb, lane ^ 8, 64);
  if (lane < 8){
    int filled = nb + nb_partner;
    if (filled > SLOTS) filled = SLOTS;
    xcd_cnt[lane] = filled;
    xcd_cur[lane] = 0;
  }
  if (lane < 16){
    int sbase = (lane < 8) ? 0 : nb_partner;
    int xcd = lane & 7;
    for (int b = 0; b < nb; b++){
      int idx = xcd * SLOTS + sbase + b;
      if (sbase + b < SLOTS){
        bm_e[idx] = lane; bm_start[idx] = start + b * BM; bm_end[idx] = start + c;
      }
    }
  }
}

// ---------------- scatter: block-aggregated chunk reservation, LDS ranks
// pair_tok packs token | (k << 16) so the gemm can write token-major ypair.
__global__ __launch_bounds__(256) void scatter_kernel(const int* __restrict__ top_idx,
                                                      const float* __restrict__ top_w,
                                                      int* __restrict__ cursor,
                                                      int* __restrict__ pair_tok,
                                                      float* __restrict__ pair_w){
  __shared__ int hist[16], base[16], rank[16];
  int tid = threadIdx.x;
  if (tid < 16){ hist[tid] = 0; rank[tid] = 0; }
  __syncthreads();
  int t = blockIdx.x * 256 + tid;
  int e0 = top_idx[t * 2], e1 = top_idx[t * 2 + 1];
  float w0 = top_w[t * 2], w1 = top_w[t * 2 + 1];
  atomicAdd(&hist[e0], 1); atomicAdd(&hist[e1], 1);
  __syncthreads();
  if (tid < 16) base[tid] = atomicAdd(&cursor[tid], hist[tid]);
  __syncthreads();
  int r0 = atomicAdd(&rank[e0], 1);
  int p0 = base[e0] + r0;
  pair_tok[p0] = t; pair_w[p0] = w0;
  int r1 = atomicAdd(&rank[e1], 1);
  int p1 = base[e1] + r1;
  pair_tok[p1] = t | (1 << 16); pair_w[p1] = w1;
}

// ---------------- fused 2-layer expert MLP v16: v15 internals (32x32 MFMA,
// 16-granule XOR swizzles, dbuf staging, raw barriers) + PERSISTENT blocks
// with per-XCD work stealing: 256 blocks (1/CU), each loops over its XCD's
// unit list via one LDS-broadcast atomicAdd per 128-token unit. Removes the
// ceil(units/32) round quantization (~30% tail).
__global__ __launch_bounds__(512, 1) void moe_gemm_kernel(
    const unsigned short* __restrict__ x_bf,   // [B][256]
    const unsigned short* __restrict__ W1t,    // [E][512 h][256 i]
    const unsigned short* __restrict__ W2c,    // [E][8 c][256 o][64 h]
    const float* __restrict__ b1,              // [E][512]
    const float* __restrict__ b2,              // [E][256]
    const int* __restrict__ pair_tok, const float* __restrict__ pair_w,
    const int* __restrict__ bm_e, const int* __restrict__ bm_start,
    const int* __restrict__ bm_end,
    int* __restrict__ xcd_cur, const int* __restrict__ xcd_cnt,
    unsigned short* __restrict__ ypair){       // [B*2][256] bf16, token-major
  int xcd = blockIdx.x & 7;

  __shared__ unsigned short w1s[2][CH * 256];   // 2x32KB [64 hid][256 k], 512B rows, ^(hid&15)<<4
  __shared__ unsigned short w2s[2][256 * CH];   // 2x32KB [256 o][64 k], 256B row-pairs, ^(pair&15)<<4
  __shared__ unsigned short hs[BM * CH];        // 16KB [128 tok][64 h], 256B row-pairs, ^(pair&15)<<4
  __shared__ int s_u;

  int tid = threadIdx.x, wid = tid >> 6, lane = tid & 63;
  int l31 = lane & 31, l5 = lane >> 5;
  int mg = wid >> 1, hg = wid & 1;
  char* hsb = (char*)hs;

  // pre-swizzled staging source offsets (linear LDS dest; +k*8192 preserves XOR bits)
  int o1, o2;
  { int r = tid >> 5; o1 = r * 512 + (((tid & 31) ^ (r & 15)) * 16); }
  { int p = tid >> 4; int q = (tid & 15) ^ (p & 15);
    o2 = (p * 2 + (q >> 3)) * 128 + (q & 7) * 16; }

  int hid = hg * 32 + l31;                 // chunk-local hid row this wave reads/writes
  int swzA = (hid & 15) << 4;
  const f32x16 fzero = {0.f,0.f,0.f,0.f,0.f,0.f,0.f,0.f,0.f,0.f,0.f,0.f,0.f,0.f,0.f,0.f};
  int cnt = xcd_cnt[xcd];

  for (;;){
    if (tid == 0) s_u = atomicAdd(&xcd_cur[xcd], 1);
    __syncthreads();
    int u = s_u;
    if (u >= cnt) break;                   // uniform exit
    int bmi = xcd * SLOTS + u;
    int e = bm_e[bmi], rs = bm_start[bmi], re = bm_end[bmi];
    const char* gW1 = (const char*)(W1t + (size_t)e * DHID * DIN);
    const char* gW2 = (const char*)(W2c + (size_t)e * DOUT * DHID);

#define STAGE(c, sl) {                                                    \
    const char* s1 = gW1 + (size_t)(c) * 32768;                           \
    const char* s2 = gW2 + (size_t)(c) * 32768;                           \
    char* d1 = (char*)w1s[sl]; char* d2 = (char*)w2s[sl];                 \
    _Pragma("unroll")                                                     \
    for (int k = 0; k < 4; k++){                                          \
      gload16(s1 + o1 + k * 8192, d1 + tid * 16 + k * 8192);              \
      gload16(s2 + o2 + k * 8192, d2 + tid * 16 + k * 8192);              \
    } }

    // ---- x rows (wave's 32 tokens) -> registers: 16 k-frags (64 VGPR)
    bf16x8 xr[16];
    {
      int g0 = rs + mg * 32 + l31;
      int gc = g0 < re ? g0 : (re - 1);
      int tok = pair_tok[gc] & 0xFFFF;
      const unsigned short* xrow = x_bf + (size_t)tok * DIN + l5 * 8;
#pragma unroll
      for (int ks = 0; ks < 16; ks++) xr[ks] = *(const bf16x8*)(xrow + ks * 16);
    }

    f32x16 acc[4];
    acc[0] = fzero; acc[1] = fzero; acc[2] = fzero; acc[3] = fzero;

    STAGE(0, 0);
    asm volatile("s_waitcnt vmcnt(0)" ::: "memory");
    __builtin_amdgcn_sched_barrier(0);
    __builtin_amdgcn_s_barrier();
    __builtin_amdgcn_sched_barrier(0);

    for (int c = 0; c < NCH; c++){
      int sl = c & 1;
      if (c + 1 < NCH) STAGE(c + 1, sl ^ 1);     // lands during this chunk

      float b1v = b1[e * DHID + c * CH + hid];

      // ---- phase A: h-tile[32 tok of mg][32 hid of hg], K=256, 2 dep-chains
      {
        const char* w1b = (const char*)w1s[sl];
        f32x16 h0 = fzero, h1 = fzero;
#pragma unroll
        for (int ks = 0; ks < 16; ks += 2){
          bf16x8 bA = *(const bf16x8*)(w1b + hid * 512 + ((ks * 32 + l5 * 16) ^ swzA));
          bf16x8 bB = *(const bf16x8*)(w1b + hid * 512 + (((ks + 1) * 32 + l5 * 16) ^ swzA));
          h0 = __builtin_amdgcn_mfma_f32_32x32x16_bf16(xr[ks], bA, h0, 0, 0, 0);
          h1 = __builtin_amdgcn_mfma_f32_32x32x16_bf16(xr[ks + 1], bB, h1, 0, 0, 0);
        }
        f32x16 hsum = h0 + h1;
        // relu(h+b1) -> hs; C/D: col=lane&31, row=(reg&3)+8*(reg>>2)+4*(lane>>5)
        int h2 = hg * 64 + l31 * 2;
#pragma unroll
        for (int r = 0; r < 16; r++){
          int tk = mg * 32 + (r & 3) + ((r >> 2) << 3) + (l5 << 2);
          float v = fmaxf(hsum[r] + b1v, 0.f);
          int adr = (tk >> 1) * 256 + ((((tk & 1) << 7) + h2) ^ (((tk >> 1) & 15) << 4));
          *(unsigned short*)(hsb + adr) = f2bf(v);
        }
      }
      asm volatile("s_waitcnt lgkmcnt(0)" ::: "memory");
      __builtin_amdgcn_sched_barrier(0);
      __builtin_amdgcn_s_barrier();
      __builtin_amdgcn_sched_barrier(0);

      // ---- phase B: y[32 tok of mg][128 out of hg] += h @ W2c (K=64)
      {
        const char* w2b = (const char*)w2s[sl];
        int tk = mg * 32 + l31;
        int hswz = ((tk >> 1) & 15) << 4;
        int hbase = (tk >> 1) * 256;
        int hhi = (tk & 1) << 7;
#pragma unroll
        for (int ks = 0; ks < 4; ks++){
          bf16x8 ha = *(const bf16x8*)(hsb + hbase + ((hhi + ks * 32 + l5 * 16) ^ hswz));
#pragma unroll
          for (int ot = 0; ot < 4; ot++){
            int n = hg * 128 + ot * 32 + l31;
            int adr = (n >> 1) * 256 + ((((n & 1) << 7) + ks * 32 + l5 * 16) ^ (((n >> 1) & 15) << 4));
            bf16x8 bb = *(const bf16x8*)(w2b + adr);
            acc[ot] = __builtin_amdgcn_mfma_f32_32x32x16_bf16(ha, bb, acc[ot], 0, 0, 0);
          }
        }
      }
      if (c + 1 < NCH){
        asm volatile("s_waitcnt vmcnt(0) lgkmcnt(0)" ::: "memory");
        __builtin_amdgcn_sched_barrier(0);
        __builtin_amdgcn_s_barrier();
        __builtin_amdgcn_sched_barrier(0);
      }
    }

    // ---- epilogue: fold gate weight + b2, store token-major bf16 rows
    {
      float b2v[4];
#pragma unroll
      for (int ot = 0; ot < 4; ot++) b2v[ot] = b2[e * DOUT + hg * 128 + ot * 32 + l31];
#pragma unroll
      for (int r = 0; r < 16; r++){
        int tl = mg * 32 + (r & 3) + ((r >> 2) << 3) + (l5 << 2);
        int gg = rs + tl;
        if (gg < re){
          int pt = pair_tok[gg];
          int yrow = (pt & 0xFFFF) * 2 + (pt >> 16);
          float w = pair_w[gg];
          unsigned short* yp = ypair + (size_t)yrow * DOUT + hg * 128 + l31;
#pragma unroll
          for (int ot = 0; ot < 4; ot++)
            yp[ot * 32] = f2bf(w * (acc[ot][r] + b2v[ot]));
        }
      }
    }
#undef STAGE
  }
}

// ---------------- combine: out[t] = yp[2t] + yp[2t+1], fully coalesced
__global__ __launch_bounds__(256) void combine_kernel(const unsigned short* __restrict__ yp,
                                                      float* __restrict__ out){
  int idx = blockIdx.x * 256 + threadIdx.x;
  int t = idx >> 6;
  int c4 = (idx & 63) << 2;
  ushort4 a = *(const ushort4*)(yp + (size_t)(t * 2) * DOUT + c4);
  ushort4 b = *(const ushort4*)(yp + (size_t)(t * 2 + 1) * DOUT + c4);
  float4 o;
  o.x = bf2f(a.x) + bf2f(b.x);
  o.y = bf2f(a.y) + bf2f(b.y);
  o.z = bf2f(a.z) + bf2f(b.z);
  o.w = bf2f(a.w) + bf2f(b.w);
  *(float4*)(out + (size_t)t * DOUT + c4) = o;
}

extern "C" void kernel_launch(void* const* d_in, const int* in_sizes, int n_in,
                              void* d_out, int out_size, void* d_ws, size_t ws_size,
                              hipStream_t stream){
  (void)in_sizes; (void)n_in; (void)out_size; (void)ws_size;
  const float* x  = (const float*)d_in[0];
  const float* Wg = (const float*)d_in[1];
  const float* bg = (const float*)d_in[2];
  const float* W1 = (const float*)d_in[3];
  const float* b1 = (const float*)d_in[4];
  const float* W2 = (const float*)d_in[5];
  const float* b2 = (const float*)d_in[6];
  float* out = (float*)d_out;
  char* ws = (char*)d_ws;

  unsigned short* x_bf  = (unsigned short*)(ws);                 // 16,777,216
  unsigned short* W1t   = (unsigned short*)(ws + 16777216);      //  4,194,304
  unsigned short* W2ck  = (unsigned short*)(ws + 20971520);      //  4,194,304
  unsigned short* ypair = (unsigned short*)(ws + 25165824);      // 33,554,432
  int*   top_idx  = (int*)  (ws + 58720256);
  float* top_w    = (float*)(ws + 58982400);
  int*   pair_tok = (int*)  (ws + 59244544);
  float* pair_w   = (float*)(ws + 59506688);
  int*   counts   = (int*)  (ws + 60030976);
  int*   offsets  = (int*)  (ws + 60031040);
  int*   cursor   = (int*)  (ws + 60031104);
  int*   bm_e     = (int*)  (ws + 60031232);   // 768 ints
  int*   bm_start = (int*)  (ws + 60036608);   // 768 ints
  int*   bm_end   = (int*)  (ws + 60041984);   // 768 ints
  int*   xcd_cnt  = (int*)  (ws + 60045184);   // 8 ints
  int*   xcd_cur  = (int*)  (ws + 60045248);   // 8 ints

  hipMemsetAsync(counts, 0, 64, stream);
  transpose_cvt<<<dim3(16, 8, 16), 256, 0, stream>>>(W1, W1t, 256, 512);
  transpose_cvt_w2<<<dim3(8, 16, 16), 256, 0, stream>>>(W2, W2ck);
  gating_kernel<<<512, 256, 0, stream>>>(x, Wg, bg, x_bf, top_idx, top_w, counts);
  prefix_kernel<<<1, 64, 0, stream>>>(counts, offsets, cursor, bm_e, bm_start, bm_end,
                                      xcd_cnt, xcd_cur);
  scatter_kernel<<<128, 256, 0, stream>>>(top_idx, top_w, cursor, pair_tok, pair_w);
  moe_gemm_kernel<<<256, 512, 0, stream>>>(x_bf, W1t, W2ck, b1, b2, pair_tok, pair_w,
                                           bm_e, bm_start, bm_end, xcd_cur, xcd_cnt, ypair);
  combine_kernel<<<8192, 256, 0, stream>>>(ypair, out);
}